// Round 3
// baseline (1202.202 us; speedup 1.0000x reference)
//
#include <hip/hip_runtime.h>
#include <hip/hip_bf16.h>
#include <math.h>

// Problem constants (B,C_IN,C_OUT,STYLE,H,W = 4,128,128,512,64,64)
#define BB 4
#define CIN 128
#define COUT 128
#define NSTYLE 512
#define HH 64
#define WW 64
#define NN 4096        // H*W
#define CQK 16
#define EPSV 1e-5f

// ---- workspace layout (float offsets) ----
static constexpr size_t OFF_SCALE = 0;                       // [4*128]
static constexpr size_t OFF_BIAS  = 512;                     // [4*128]
static constexpr size_t OFF_H     = 1024;                    // [4*128*4096]
static constexpr size_t OFF_Q     = OFF_H  + (size_t)BB*COUT*NN;   // [4*16*4096]
static constexpr size_t OFF_K     = OFF_Q  + (size_t)BB*CQK*NN;
static constexpr size_t OFF_V     = OFF_K  + (size_t)BB*CQK*NN;    // [4*128*4096]
static constexpr size_t OFF_AO    = OFF_V  + (size_t)BB*COUT*NN;   // [4*128*4096]

// ---------------------------------------------------------------------------
// k1: scale[b,c] = style[b]·ss_w[c] + ss_b[c]; bias likewise. 1 wave / (b,c).
// ---------------------------------------------------------------------------
__global__ __launch_bounds__(64)
void style_affine(const float* __restrict__ style,
                  const float* __restrict__ ss_w, const float* __restrict__ ss_b,
                  const float* __restrict__ sb_w, const float* __restrict__ sb_b,
                  float* __restrict__ ws) {
    int bc = blockIdx.x;            // b*128 + c
    int b = bc >> 7, c = bc & 127;
    int lane = threadIdx.x;         // 0..63
    const float* st = style + (size_t)b * NSTYLE;
    float s1 = 0.f, s2 = 0.f;
    for (int e = lane; e < NSTYLE; e += 64) {
        float sv = st[e];
        s1 += sv * ss_w[(size_t)c * NSTYLE + e];
        s2 += sv * sb_w[(size_t)c * NSTYLE + e];
    }
    #pragma unroll
    for (int off = 32; off; off >>= 1) {
        s1 += __shfl_xor(s1, off);
        s2 += __shfl_xor(s2, off);
    }
    if (lane == 0) {
        ws[OFF_SCALE + bc] = s1 + ss_b[c];
        ws[OFF_BIAS  + bc] = s2 + sb_b[c];
    }
}

// ---------------------------------------------------------------------------
// k2: conv3x3 (pad 1) + bias + AdaIN modulation -> h in ws.
// Tile: 8 rows x 64 cols x 4 co. 256 thr: tx=t&31 (col pair 2tx), ty=t>>5.
// Grid (8 row-tiles, 32 co-groups, 4 b) = 1024 blocks -> 4 blocks/CU resident.
// Weights: all 4co x 128ci x 9 staged to LDS once (18.4 KB); per-ci read as
//   9 x ds_read_b128 at wave-uniform address (broadcast, conflict-free).
// x: full-width rows in LDS, stride 66 words, zero-pad cols p=0,p=65;
//   taps = 2 x ds_read_b64 per (ci,ky): 64 lanes -> 64 consecutive words
//   -> 4 words/bank = minimum (conflict-free).
// x chunks of 4 ci, 2-buffer ping-pong, register-prefetched staging,
// ONE barrier per chunk.
// ---------------------------------------------------------------------------
__global__ __launch_bounds__(256, 4)
void conv_mod(const float* __restrict__ x,
              const float* __restrict__ conv_w,
              const float* __restrict__ conv_b,
              const float* __restrict__ ws,
              float* __restrict__ hout) {
    const int b   = blockIdx.z;
    const int co0 = blockIdx.y * 4;
    const int ty0 = blockIdx.x * 8;         // tile row origin
    const int t   = threadIdx.x;
    const int tx  = t & 31;                 // output cols 2tx, 2tx+1
    const int ty  = t >> 5;                 // output row ty0+ty

    __shared__ float s_w[128 * 36];         // [ci][u*9 + ky*3 + kx]  (18432 B)
    __shared__ float s_x[2][4 * 10 * 66];   // [buf][cc][r][p]        (21120 B)

    const float* xb = x + (size_t)b * CIN * NN;

    // ---- stage ALL weights once: s_w[ci*36 + u*9 + k] ----
    #pragma unroll
    for (int i = 0; i < 18; ++i) {
        int idx = t + i * 256;              // 0..4607
        int u   = idx / 1152;
        int rem = idx - u * 1152;           // ci*9 + k
        int ci  = rem / 9;
        int k   = rem - ci * 9;
        s_w[ci * 36 + u * 9 + k] = conv_w[(size_t)(co0 + u) * 1152 + rem];
    }

    // ---- staging role: 160 tasks = 40 rows x 4 segments of 16 cols ----
    const bool s_act = (t < 160);
    int s_cc = 0, s_r = 0, s_gy = -1, s_seg = 0;
    if (s_act) {
        int rt = t >> 2; s_seg = t & 3;
        s_cc = rt / 10; s_r = rt - s_cc * 10;
        s_gy = ty0 + s_r - 1;               // halo rows ty0-1 .. ty0+8
    }
    const bool s_val = s_act && ((unsigned)s_gy < 64u);

    float pf[16];
    // prologue: load chunk 0 into regs
    if (s_act) {
        if (s_val) {
            const float* src = xb + (size_t)(0 * 4 + s_cc) * NN + s_gy * 64 + s_seg * 16;
            #pragma unroll
            for (int j = 0; j < 4; ++j) {
                float4 v = reinterpret_cast<const float4*>(src)[j];
                pf[4*j+0]=v.x; pf[4*j+1]=v.y; pf[4*j+2]=v.z; pf[4*j+3]=v.w;
            }
        } else {
            #pragma unroll
            for (int j = 0; j < 16; ++j) pf[j] = 0.f;
        }
        // write buf 0
        float* dst = &s_x[0][(s_cc * 10 + s_r) * 66 + 1 + s_seg * 16];
        #pragma unroll
        for (int j = 0; j < 16; ++j) dst[j] = pf[j];
        if (s_seg == 0) dst[-1] = 0.f;      // p = 0  (global col -1)
        if (s_seg == 3) dst[16] = 0.f;      // p = 65 (global col 64)
    }
    __syncthreads();

    float acc[4][2];
    #pragma unroll
    for (int u = 0; u < 4; ++u) { acc[u][0] = 0.f; acc[u][1] = 0.f; }

    for (int c = 0; c < 32; ++c) {
        // prefetch next chunk's globals into regs (latency hides under compute)
        if (c < 31 && s_act) {
            if (s_val) {
                const float* src = xb + (size_t)((c + 1) * 4 + s_cc) * NN + s_gy * 64 + s_seg * 16;
                #pragma unroll
                for (int j = 0; j < 4; ++j) {
                    float4 v = reinterpret_cast<const float4*>(src)[j];
                    pf[4*j+0]=v.x; pf[4*j+1]=v.y; pf[4*j+2]=v.z; pf[4*j+3]=v.w;
                }
            }
        }

        const float* xbuf = s_x[c & 1];
        #pragma unroll
        for (int cc = 0; cc < 4; ++cc) {
            const int ci = c * 4 + cc;
            // 9 x b128 broadcast reads of this ci's 36 weights
            const float4* w4p = reinterpret_cast<const float4*>(&s_w[ci * 36]);
            float wr[36];
            #pragma unroll
            for (int j = 0; j < 9; ++j) {
                float4 v = w4p[j];
                wr[4*j]=v.x; wr[4*j+1]=v.y; wr[4*j+2]=v.z; wr[4*j+3]=v.w;
            }
            #pragma unroll
            for (int ky = 0; ky < 3; ++ky) {
                const float* rp = &xbuf[(cc * 10 + ty + ky) * 66 + 2 * tx];
                float2 A  = *reinterpret_cast<const float2*>(rp);      // p, p+1
                float2 Bv = *reinterpret_cast<const float2*>(rp + 2);  // p+2, p+3
                #pragma unroll
                for (int u = 0; u < 4; ++u) {
                    const float w0 = wr[u*9 + ky*3 + 0];
                    const float w1 = wr[u*9 + ky*3 + 1];
                    const float w2 = wr[u*9 + ky*3 + 2];
                    acc[u][0] += A.x * w0 + A.y  * w1 + Bv.x * w2;
                    acc[u][1] += A.y * w0 + Bv.x * w1 + Bv.y * w2;
                }
            }
        }

        // write prefetched regs into the other buffer
        if (c < 31 && s_act) {
            if (!s_val) {
                #pragma unroll
                for (int j = 0; j < 16; ++j) pf[j] = 0.f;
            }
            float* dst = &s_x[(c + 1) & 1][(s_cc * 10 + s_r) * 66 + 1 + s_seg * 16];
            #pragma unroll
            for (int j = 0; j < 16; ++j) dst[j] = pf[j];
            if (s_seg == 0) dst[-1] = 0.f;
            if (s_seg == 3) dst[16] = 0.f;
        }
        __syncthreads();
    }

    // ---- epilogue: bias + AdaIN modulation, float2 stores ----
    const int gy = ty0 + ty, gx = 2 * tx;
    #pragma unroll
    for (int u = 0; u < 4; ++u) {
        const int co = co0 + u;
        const float sc  = 1.f + ws[OFF_SCALE + b * 128 + co];
        const float bi  = ws[OFF_BIAS  + b * 128 + co];
        const float cbv = conv_b[co];
        float2 o;
        o.x = (acc[u][0] + cbv) * sc + bi;
        o.y = (acc[u][1] + cbv) * sc + bi;
        *reinterpret_cast<float2*>(hout + (size_t)(b * 128 + co) * NN + gy * 64 + gx) = o;
    }
}

// ---------------------------------------------------------------------------
// k3 (runs only if gamma != 0): q/k/v 1x1 convs from h.
// ---------------------------------------------------------------------------
__global__ __launch_bounds__(256)
void qkv_kernel(float* __restrict__ ws,
                const float* __restrict__ qw, const float* __restrict__ qb,
                const float* __restrict__ kw, const float* __restrict__ kb,
                const float* __restrict__ vw, const float* __restrict__ vb,
                const float* __restrict__ gamma) {
    if (gamma[0] == 0.f) return;
    const int b  = blockIdx.y;
    const int oc = blockIdx.x;   // 0..159: 16 q, 16 k, 128 v
    const float* wrow; float bias; float* dst;
    if (oc < 16)      { wrow = qw + (size_t)oc * 128;        bias = qb[oc];
                        dst = ws + OFF_Q + (size_t)(b * 16 + oc) * NN; }
    else if (oc < 32) { int c = oc - 16; wrow = kw + (size_t)c * 128; bias = kb[c];
                        dst = ws + OFF_K + (size_t)(b * 16 + c) * NN; }
    else              { int c = oc - 32; wrow = vw + (size_t)c * 128; bias = vb[c];
                        dst = ws + OFF_V + (size_t)(b * 128 + c) * NN; }
    const float* hb = ws + OFF_H + (size_t)b * 128 * NN;
    for (int n = threadIdx.x; n < NN; n += 256) {
        float a = bias;
        for (int ci = 0; ci < 128; ++ci) a += hb[(size_t)ci * NN + n] * wrow[ci];
        dst[n] = a;
    }
}

// ---------------------------------------------------------------------------
// k4 (runs only if gamma != 0): flash-style attention, 64 queries per block.
// ---------------------------------------------------------------------------
__global__ __launch_bounds__(256)
void attn_kernel(float* __restrict__ ws, const float* __restrict__ gamma) {
    if (gamma[0] == 0.f) return;
    const int b  = blockIdx.y;
    const int n0 = blockIdx.x * 64;
    const int t  = threadIdx.x;

    __shared__ float q_s[16][64];
    __shared__ float k_s[16][64];
    __shared__ float v_s[64][129];
    __shared__ float p_s[64][65];
    __shared__ float m_run[64], l_run[64], sc_s[64];

    const float* qp = ws + OFF_Q + (size_t)b * 16 * NN;
    const float* kp = ws + OFF_K + (size_t)b * 16 * NN;
    const float* vp = ws + OFF_V + (size_t)b * 128 * NN;

    for (int idx = t; idx < 16 * 64; idx += 256) {
        int cq = idx >> 6, j = idx & 63;
        q_s[cq][j] = qp[(size_t)cq * NN + n0 + j];
    }
    if (t < 64) { m_run[t] = -1e30f; l_run[t] = 0.f; }

    const int n  = t & 63;
    const int cg = t >> 6;
    float acc[32];
    #pragma unroll
    for (int i = 0; i < 32; ++i) acc[i] = 0.f;
    __syncthreads();

    for (int mt = 0; mt < 64; ++mt) {
        const int m0 = mt * 64;
        for (int idx = t; idx < 16 * 64; idx += 256) {
            int cq = idx >> 6, j = idx & 63;
            k_s[cq][j] = kp[(size_t)cq * NN + m0 + j];
        }
        for (int idx = t; idx < 128 * 64; idx += 256) {
            int c = idx >> 6, j = idx & 63;
            v_s[j][c] = vp[(size_t)c * NN + m0 + j];
        }
        __syncthreads();
        {
            const int nn2   = t & 63;
            const int mbase = (t >> 6) * 16;
            for (int mi = 0; mi < 16; ++mi) {
                const int mm = mbase + mi;
                float s = 0.f;
                #pragma unroll
                for (int cq = 0; cq < 16; ++cq) s += q_s[cq][nn2] * k_s[cq][mm];
                p_s[nn2][mm] = s;
            }
        }
        __syncthreads();
        if (t < 64) {
            float mold = m_run[t];
            float mx = mold;
            for (int mm = 0; mm < 64; ++mm) mx = fmaxf(mx, p_s[t][mm]);
            float sc = expf(mold - mx);
            float rs = 0.f;
            for (int mm = 0; mm < 64; ++mm) {
                float p = expf(p_s[t][mm] - mx);
                p_s[t][mm] = p;
                rs += p;
            }
            l_run[t] = l_run[t] * sc + rs;
            m_run[t] = mx;
            sc_s[t]  = sc;
        }
        __syncthreads();
        {
            const float sc = sc_s[n];
            #pragma unroll
            for (int i = 0; i < 32; ++i) acc[i] *= sc;
            for (int mm = 0; mm < 64; ++mm) {
                const float p = p_s[n][mm];
                #pragma unroll
                for (int i = 0; i < 32; ++i) acc[i] += p * v_s[mm][cg * 32 + i];
            }
        }
        __syncthreads();
    }

    const float inv = 1.f / l_run[n];
    float* ao = ws + OFF_AO + (size_t)b * 128 * NN;
    for (int i = 0; i < 32; ++i)
        ao[(size_t)(cg * 32 + i) * NN + n0 + n] = acc[i] * inv;
}

// ---------------------------------------------------------------------------
// k5: h2 = gamma*attn_out + h; InstanceNorm (biased var, eps=1e-5); LeakyReLU.
// ---------------------------------------------------------------------------
__global__ __launch_bounds__(256)
void inorm_lrelu(const float* __restrict__ ws,
                 const float* __restrict__ gamma,
                 float* __restrict__ out) {
    const int bc = blockIdx.x;      // b*128 + c
    const int t  = threadIdx.x;
    const float g = gamma[0];

    const float4* hp = (const float4*)(ws + OFF_H  + (size_t)bc * NN);
    const float4* ap = (const float4*)(ws + OFF_AO + (size_t)bc * NN);

    float4 v[4];
    #pragma unroll
    for (int i = 0; i < 4; ++i) {
        float4 hv = hp[t + 256 * i];
        if (g != 0.f) {
            float4 av = ap[t + 256 * i];
            hv.x += g * av.x; hv.y += g * av.y; hv.z += g * av.z; hv.w += g * av.w;
        }
        v[i] = hv;
    }

    float s1 = 0.f, s2 = 0.f;
    #pragma unroll
    for (int i = 0; i < 4; ++i) {
        s1 += v[i].x + v[i].y + v[i].z + v[i].w;
        s2 += v[i].x * v[i].x + v[i].y * v[i].y + v[i].z * v[i].z + v[i].w * v[i].w;
    }
    #pragma unroll
    for (int off = 32; off; off >>= 1) {
        s1 += __shfl_xor(s1, off);
        s2 += __shfl_xor(s2, off);
    }
    __shared__ float r1[4], r2[4];
    if ((t & 63) == 0) { r1[t >> 6] = s1; r2[t >> 6] = s2; }
    __syncthreads();
    const float S1 = r1[0] + r1[1] + r1[2] + r1[3];
    const float S2 = r2[0] + r2[1] + r2[2] + r2[3];
    const float mu  = S1 * (1.f / 4096.f);
    const float var = S2 * (1.f / 4096.f) - mu * mu;
    const float rs  = 1.f / sqrtf(var + EPSV);

    float4* op = (float4*)out + (size_t)bc * (NN / 4);
    #pragma unroll
    for (int i = 0; i < 4; ++i) {
        float4 o;
        o.x = (v[i].x - mu) * rs; o.x = o.x >= 0.f ? o.x : 0.2f * o.x;
        o.y = (v[i].y - mu) * rs; o.y = o.y >= 0.f ? o.y : 0.2f * o.y;
        o.z = (v[i].z - mu) * rs; o.z = o.z >= 0.f ? o.z : 0.2f * o.z;
        o.w = (v[i].w - mu) * rs; o.w = o.w >= 0.f ? o.w : 0.2f * o.w;
        op[t + 256 * i] = o;
    }
}

// ---------------------------------------------------------------------------
extern "C" void kernel_launch(void* const* d_in, const int* in_sizes, int n_in,
                              void* d_out, int out_size, void* d_ws, size_t ws_size,
                              hipStream_t stream) {
    const float* x      = (const float*)d_in[0];
    const float* style  = (const float*)d_in[1];
    const float* conv_w = (const float*)d_in[2];
    const float* conv_b = (const float*)d_in[3];
    const float* ss_w   = (const float*)d_in[4];
    const float* ss_b   = (const float*)d_in[5];
    const float* sb_w   = (const float*)d_in[6];
    const float* sb_b   = (const float*)d_in[7];
    const float* q_w    = (const float*)d_in[8];
    const float* q_b    = (const float*)d_in[9];
    const float* k_w    = (const float*)d_in[10];
    const float* k_b    = (const float*)d_in[11];
    const float* v_w    = (const float*)d_in[12];
    const float* v_b    = (const float*)d_in[13];
    const float* gamma  = (const float*)d_in[14];
    float* ws  = (float*)d_ws;
    float* out = (float*)d_out;

    style_affine<<<512, 64, 0, stream>>>(style, ss_w, ss_b, sb_w, sb_b, ws);
    conv_mod<<<dim3(8, 32, 4), 256, 0, stream>>>(x, conv_w, conv_b, ws, ws + OFF_H);
    qkv_kernel<<<dim3(160, 4), 256, 0, stream>>>(ws, q_w, q_b, k_w, k_b, v_w, v_b, gamma);
    attn_kernel<<<dim3(64, 4), 256, 0, stream>>>(ws, gamma);
    inorm_lrelu<<<512, 256, 0, stream>>>(ws, gamma, out);
}

// Round 4
// 296.627 us; speedup vs baseline: 4.0529x; 4.0529x over previous
//
#include <hip/hip_runtime.h>
#include <hip/hip_bf16.h>
#include <math.h>

// Problem constants (B,C_IN,C_OUT,STYLE,H,W = 4,128,128,512,64,64)
#define NN 4096
#define EPSV 1e-5f

// ---- workspace layout (float offsets) ----
static constexpr size_t OFF_H  = 1024;                          // [4*128*4096]
static constexpr size_t OFF_Q  = OFF_H + (size_t)4*128*4096;    // [4*16*4096]
static constexpr size_t OFF_K  = OFF_Q + (size_t)4*16*4096;
static constexpr size_t OFF_V  = OFF_K + (size_t)4*16*4096;     // [4*128*4096]
static constexpr size_t OFF_AO = OFF_V + (size_t)4*128*4096;    // [4*128*4096]

// ---------------------------------------------------------------------------
// conv3x3 (pad 1) + bias + AdaIN modulation (style GEMV fused) -> h in ws.
//
// Tile: 8 rows x 64 cols x 4 co. 256 thr: tx=t&15 (cols 4tx..4tx+3),
// ty=(t>>4)&7 (row), uh=t>>7 (co pair co0+2uh+{0,1}).
// Grid (8 row-tiles, 32 co-groups, 4 b) = 1024 blocks = exactly 4/CU.
// LDS 35.5 KB -> 4 blocks/CU. NO launch_bounds cap (r3's spill disaster).
//
// x rows in LDS: stride 68 words, col c at word 2+c; halo col -1 at word 1,
// col 64 at word 66. Taps = 2 x ds_read_b128 per (ci,ky), 16B aligned
// (4tx ≡ 0 mod 4, 68 ≡ 0 mod 4), words uniform over banks -> conflict-free.
// Weights s_w[ci][uh][ky][8]: b128 + b64 wave-uniform broadcast per ky.
// x staged in chunks of 2 ci, double-buffered, register-prefetched,
// ONE barrier per chunk; staging writes are 8B-aligned float2 (2-way max).
// ---------------------------------------------------------------------------
__global__ __launch_bounds__(256)
void conv_mod(const float* __restrict__ x,
              const float* __restrict__ conv_w,
              const float* __restrict__ conv_b,
              const float* __restrict__ style,
              const float* __restrict__ ss_w, const float* __restrict__ ss_b,
              const float* __restrict__ sb_w, const float* __restrict__ sb_b,
              float* __restrict__ hout) {
    const int b   = blockIdx.z;
    const int co0 = blockIdx.y * 4;
    const int ty0 = blockIdx.x * 8;
    const int t   = threadIdx.x;
    const int tx  = t & 15;
    const int ty  = (t >> 4) & 7;
    const int uh  = t >> 7;

    __shared__ float s_w[128 * 48];        // [ci][uh][ky][8]   24576 B
    __shared__ float s_x[2][20 * 68];      // [buf][cc*10+r][68] 10880 B
    __shared__ float s_sb[4][2];           // per-co (scale, bias)

    // ---- fused style GEMV: one 64-lane group per co ----
    {
        const int u = t >> 6, lane = t & 63;
        const float* st = style + (size_t)b * 512;
        const float* w1 = ss_w + (size_t)(co0 + u) * 512;
        const float* w2 = sb_w + (size_t)(co0 + u) * 512;
        float s1 = 0.f, s2 = 0.f;
        for (int e = lane; e < 512; e += 64) {
            float sv = st[e];
            s1 += sv * w1[e];
            s2 += sv * w2[e];
        }
        #pragma unroll
        for (int off = 32; off; off >>= 1) {
            s1 += __shfl_xor(s1, off);
            s2 += __shfl_xor(s2, off);
        }
        if (lane == 0) {
            s_sb[u][0] = s1 + ss_b[co0 + u];
            s_sb[u][1] = s2 + sb_b[co0 + u];
        }
    }

    // ---- stage all weights for the 4 co: repack to [ci][uh][ky][8] ----
    {
        const float4* src = (const float4*)(conv_w + (size_t)co0 * 1152);
        for (int j = t; j < 1152; j += 256) {
            float4 v = src[j];
            float vv[4] = {v.x, v.y, v.z, v.w};
            #pragma unroll
            for (int i = 0; i < 4; ++i) {
                int idx = 4 * j + i;               // 0..4607
                int u   = idx / 1152;
                int m   = idx - u * 1152;          // ci*9 + kk
                int ci  = m / 9;
                int kk  = m - 9 * ci;
                int ky  = kk / 3;
                int kx  = kk - 3 * ky;
                s_w[ci * 48 + (u >> 1) * 24 + ky * 8 + (u & 1) * 3 + kx] = vv[i];
            }
        }
    }

    const float* xb = x + (size_t)b * 128 * NN;

    // ---- staging tasks: 320 float4-tasks per chunk (t, and t+256 if t<64)
    // task tau: cc = tau>=160, rem = tau-160cc, r = rem>>4 (0..9), q = rem&15
    // gy = ty0 + r - 1; load x[ci][gy][4q..4q+3]; write words 2+4q..5+4q.
    const int tauA = t;
    const int ccA = (tauA >= 160); const int remA = tauA - 160 * ccA;
    const int rA = remA >> 4, qA = remA & 15;
    const int gyA = ty0 + rA - 1;
    const bool vA = ((unsigned)gyA < 64u);
    const int tauB = t + 256;                 // only t<64
    const int ccB = 1; const int remB = tauB - 160;
    const int rB = remB >> 4, qB = remB & 15;
    const int gyB = ty0 + rB - 1;
    const bool vB = ((unsigned)gyB < 64u);
    const bool actB = (t < 64);

    float4 pfA = make_float4(0.f, 0.f, 0.f, 0.f);
    float4 pfB = make_float4(0.f, 0.f, 0.f, 0.f);

    // prologue: chunk 0 -> buf 0
    if (vA) pfA = *(const float4*)(xb + (size_t)ccA * NN + gyA * 64 + 4 * qA);
    if (actB && vB) pfB = *(const float4*)(xb + (size_t)ccB * NN + gyB * 64 + 4 * qB);
    {
        float* dst = &s_x[0][(ccA * 10 + rA) * 68 + 2 + 4 * qA];
        *(float2*)dst = make_float2(pfA.x, pfA.y);
        *(float2*)(dst + 2) = make_float2(pfA.z, pfA.w);
        if (qA == 0)  dst[-1] = 0.f;
        if (qA == 15) dst[4]  = 0.f;
        if (actB) {
            float* db = &s_x[0][(ccB * 10 + rB) * 68 + 2 + 4 * qB];
            *(float2*)db = make_float2(pfB.x, pfB.y);
            *(float2*)(db + 2) = make_float2(pfB.z, pfB.w);
            if (qB == 0)  db[-1] = 0.f;
            if (qB == 15) db[4]  = 0.f;
        }
    }
    __syncthreads();

    float acc[2][4];
    #pragma unroll
    for (int ul = 0; ul < 2; ++ul)
        #pragma unroll
        for (int p = 0; p < 4; ++p) acc[ul][p] = 0.f;

    for (int c = 0; c < 64; ++c) {
        // prefetch next chunk's globals into regs
        if (c < 63) {
            pfA = make_float4(0.f, 0.f, 0.f, 0.f);
            pfB = make_float4(0.f, 0.f, 0.f, 0.f);
            if (vA) pfA = *(const float4*)(xb + (size_t)((c + 1) * 2 + ccA) * NN + gyA * 64 + 4 * qA);
            if (actB && vB) pfB = *(const float4*)(xb + (size_t)((c + 1) * 2 + ccB) * NN + gyB * 64 + 4 * qB);
        }

        const float* xbuf = s_x[c & 1];
        #pragma unroll
        for (int cc = 0; cc < 2; ++cc) {
            const int ci = c * 2 + cc;
            const float* wb = &s_w[ci * 48 + uh * 24];
            #pragma unroll
            for (int ky = 0; ky < 3; ++ky) {
                const float* rp = &xbuf[(cc * 10 + ty + ky) * 68 + 4 * tx];
                float4 A  = *(const float4*)rp;         // cols 4tx-2..4tx+1
                float4 Bv = *(const float4*)(rp + 4);   // cols 4tx+2..4tx+5
                float4 wa = *(const float4*)(wb + ky * 8);       // u0:k0..2, u1:k0
                float2 wc = *(const float2*)(wb + ky * 8 + 4);   // u1:k1,k2
                // u-local 0
                acc[0][0] += A.y  * wa.x + A.z  * wa.y + A.w  * wa.z;
                acc[0][1] += A.z  * wa.x + A.w  * wa.y + Bv.x * wa.z;
                acc[0][2] += A.w  * wa.x + Bv.x * wa.y + Bv.y * wa.z;
                acc[0][3] += Bv.x * wa.x + Bv.y * wa.y + Bv.z * wa.z;
                // u-local 1
                acc[1][0] += A.y  * wa.w + A.z  * wc.x + A.w  * wc.y;
                acc[1][1] += A.z  * wa.w + A.w  * wc.x + Bv.x * wc.y;
                acc[1][2] += A.w  * wa.w + Bv.x * wc.x + Bv.y * wc.y;
                acc[1][3] += Bv.x * wa.w + Bv.y * wc.x + Bv.z * wc.y;
            }
        }

        // write prefetched regs into the other buffer
        if (c < 63) {
            float* dst = &s_x[(c + 1) & 1][(ccA * 10 + rA) * 68 + 2 + 4 * qA];
            *(float2*)dst = make_float2(pfA.x, pfA.y);
            *(float2*)(dst + 2) = make_float2(pfA.z, pfA.w);
            if (qA == 0)  dst[-1] = 0.f;
            if (qA == 15) dst[4]  = 0.f;
            if (actB) {
                float* db = &s_x[(c + 1) & 1][(ccB * 10 + rB) * 68 + 2 + 4 * qB];
                *(float2*)db = make_float2(pfB.x, pfB.y);
                *(float2*)(db + 2) = make_float2(pfB.z, pfB.w);
                if (qB == 0)  db[-1] = 0.f;
                if (qB == 15) db[4]  = 0.f;
            }
        }
        __syncthreads();
    }

    // ---- epilogue: bias + modulation, float4 stores ----
    const int gy = ty0 + ty;
    #pragma unroll
    for (int ul = 0; ul < 2; ++ul) {
        const int co = co0 + 2 * uh + ul;
        const float sc = 1.f + s_sb[2 * uh + ul][0];
        const float bi = s_sb[2 * uh + ul][1];
        const float cb = conv_b[co];
        float4 o;
        o.x = (acc[ul][0] + cb) * sc + bi;
        o.y = (acc[ul][1] + cb) * sc + bi;
        o.z = (acc[ul][2] + cb) * sc + bi;
        o.w = (acc[ul][3] + cb) * sc + bi;
        *(float4*)(hout + (size_t)(b * 128 + co) * NN + gy * 64 + 4 * tx) = o;
    }
}

// ---------------------------------------------------------------------------
// qkv (runs only if gamma != 0): q/k/v 1x1 convs from h.
// ---------------------------------------------------------------------------
__global__ __launch_bounds__(256)
void qkv_kernel(float* __restrict__ ws,
                const float* __restrict__ qw, const float* __restrict__ qb,
                const float* __restrict__ kw, const float* __restrict__ kb,
                const float* __restrict__ vw, const float* __restrict__ vb,
                const float* __restrict__ gamma) {
    if (gamma[0] == 0.f) return;
    const int b  = blockIdx.y;
    const int oc = blockIdx.x;   // 0..159: 16 q, 16 k, 128 v
    const float* wrow; float bias; float* dst;
    if (oc < 16)      { wrow = qw + (size_t)oc * 128;        bias = qb[oc];
                        dst = ws + OFF_Q + (size_t)(b * 16 + oc) * NN; }
    else if (oc < 32) { int c = oc - 16; wrow = kw + (size_t)c * 128; bias = kb[c];
                        dst = ws + OFF_K + (size_t)(b * 16 + c) * NN; }
    else              { int c = oc - 32; wrow = vw + (size_t)c * 128; bias = vb[c];
                        dst = ws + OFF_V + (size_t)(b * 128 + c) * NN; }
    const float* hb = ws + OFF_H + (size_t)b * 128 * NN;
    for (int n = threadIdx.x; n < NN; n += 256) {
        float a = bias;
        for (int ci = 0; ci < 128; ++ci) a += hb[(size_t)ci * NN + n] * wrow[ci];
        dst[n] = a;
    }
}

// ---------------------------------------------------------------------------
// attn (runs only if gamma != 0): flash-style, 64 queries per block.
// ---------------------------------------------------------------------------
__global__ __launch_bounds__(256)
void attn_kernel(float* __restrict__ ws, const float* __restrict__ gamma) {
    if (gamma[0] == 0.f) return;
    const int b  = blockIdx.y;
    const int n0 = blockIdx.x * 64;
    const int t  = threadIdx.x;

    __shared__ float q_s[16][64];
    __shared__ float k_s[16][64];
    __shared__ float v_s[64][129];
    __shared__ float p_s[64][65];
    __shared__ float m_run[64], l_run[64], sc_s[64];

    const float* qp = ws + OFF_Q + (size_t)b * 16 * NN;
    const float* kp = ws + OFF_K + (size_t)b * 16 * NN;
    const float* vp = ws + OFF_V + (size_t)b * 128 * NN;

    for (int idx = t; idx < 16 * 64; idx += 256) {
        int cq = idx >> 6, j = idx & 63;
        q_s[cq][j] = qp[(size_t)cq * NN + n0 + j];
    }
    if (t < 64) { m_run[t] = -1e30f; l_run[t] = 0.f; }

    const int n  = t & 63;
    const int cg = t >> 6;
    float acc[32];
    #pragma unroll
    for (int i = 0; i < 32; ++i) acc[i] = 0.f;
    __syncthreads();

    for (int mt = 0; mt < 64; ++mt) {
        const int m0 = mt * 64;
        for (int idx = t; idx < 16 * 64; idx += 256) {
            int cq = idx >> 6, j = idx & 63;
            k_s[cq][j] = kp[(size_t)cq * NN + m0 + j];
        }
        for (int idx = t; idx < 128 * 64; idx += 256) {
            int c = idx >> 6, j = idx & 63;
            v_s[j][c] = vp[(size_t)c * NN + m0 + j];
        }
        __syncthreads();
        {
            const int nn2   = t & 63;
            const int mbase = (t >> 6) * 16;
            for (int mi = 0; mi < 16; ++mi) {
                const int mm = mbase + mi;
                float s = 0.f;
                #pragma unroll
                for (int cq = 0; cq < 16; ++cq) s += q_s[cq][nn2] * k_s[cq][mm];
                p_s[nn2][mm] = s;
            }
        }
        __syncthreads();
        if (t < 64) {
            float mold = m_run[t];
            float mx = mold;
            for (int mm = 0; mm < 64; ++mm) mx = fmaxf(mx, p_s[t][mm]);
            float sc = expf(mold - mx);
            float rs = 0.f;
            for (int mm = 0; mm < 64; ++mm) {
                float p = expf(p_s[t][mm] - mx);
                p_s[t][mm] = p;
                rs += p;
            }
            l_run[t] = l_run[t] * sc + rs;
            m_run[t] = mx;
            sc_s[t]  = sc;
        }
        __syncthreads();
        {
            const float sc = sc_s[n];
            #pragma unroll
            for (int i = 0; i < 32; ++i) acc[i] *= sc;
            for (int mm = 0; mm < 64; ++mm) {
                const float p = p_s[n][mm];
                #pragma unroll
                for (int i = 0; i < 32; ++i) acc[i] += p * v_s[mm][cg * 32 + i];
            }
        }
        __syncthreads();
    }

    const float inv = 1.f / l_run[n];
    float* ao = ws + OFF_AO + (size_t)b * 128 * NN;
    for (int i = 0; i < 32; ++i)
        ao[(size_t)(cg * 32 + i) * NN + n0 + n] = acc[i] * inv;
}

// ---------------------------------------------------------------------------
// h2 = gamma*attn_out + h; InstanceNorm (biased var, eps=1e-5); LeakyReLU.
// ---------------------------------------------------------------------------
__global__ __launch_bounds__(256)
void inorm_lrelu(const float* __restrict__ ws,
                 const float* __restrict__ gamma,
                 float* __restrict__ out) {
    const int bc = blockIdx.x;      // b*128 + c
    const int t  = threadIdx.x;
    const float g = gamma[0];

    const float4* hp = (const float4*)(ws + OFF_H  + (size_t)bc * NN);
    const float4* ap = (const float4*)(ws + OFF_AO + (size_t)bc * NN);

    float4 v[4];
    #pragma unroll
    for (int i = 0; i < 4; ++i) {
        float4 hv = hp[t + 256 * i];
        if (g != 0.f) {
            float4 av = ap[t + 256 * i];
            hv.x += g * av.x; hv.y += g * av.y; hv.z += g * av.z; hv.w += g * av.w;
        }
        v[i] = hv;
    }

    float s1 = 0.f, s2 = 0.f;
    #pragma unroll
    for (int i = 0; i < 4; ++i) {
        s1 += v[i].x + v[i].y + v[i].z + v[i].w;
        s2 += v[i].x * v[i].x + v[i].y * v[i].y + v[i].z * v[i].z + v[i].w * v[i].w;
    }
    #pragma unroll
    for (int off = 32; off; off >>= 1) {
        s1 += __shfl_xor(s1, off);
        s2 += __shfl_xor(s2, off);
    }
    __shared__ float r1[4], r2[4];
    if ((t & 63) == 0) { r1[t >> 6] = s1; r2[t >> 6] = s2; }
    __syncthreads();
    const float S1 = r1[0] + r1[1] + r1[2] + r1[3];
    const float S2 = r2[0] + r2[1] + r2[2] + r2[3];
    const float mu  = S1 * (1.f / 4096.f);
    const float var = S2 * (1.f / 4096.f) - mu * mu;
    const float rs  = 1.f / sqrtf(var + EPSV);

    float4* op = (float4*)out + (size_t)bc * (NN / 4);
    #pragma unroll
    for (int i = 0; i < 4; ++i) {
        float4 o;
        o.x = (v[i].x - mu) * rs; o.x = o.x >= 0.f ? o.x : 0.2f * o.x;
        o.y = (v[i].y - mu) * rs; o.y = o.y >= 0.f ? o.y : 0.2f * o.y;
        o.z = (v[i].z - mu) * rs; o.z = o.z >= 0.f ? o.z : 0.2f * o.z;
        o.w = (v[i].w - mu) * rs; o.w = o.w >= 0.f ? o.w : 0.2f * o.w;
        op[t + 256 * i] = o;
    }
}

// ---------------------------------------------------------------------------
extern "C" void kernel_launch(void* const* d_in, const int* in_sizes, int n_in,
                              void* d_out, int out_size, void* d_ws, size_t ws_size,
                              hipStream_t stream) {
    const float* x      = (const float*)d_in[0];
    const float* style  = (const float*)d_in[1];
    const float* conv_w = (const float*)d_in[2];
    const float* conv_b = (const float*)d_in[3];
    const float* ss_w   = (const float*)d_in[4];
    const float* ss_b   = (const float*)d_in[5];
    const float* sb_w   = (const float*)d_in[6];
    const float* sb_b   = (const float*)d_in[7];
    const float* q_w    = (const float*)d_in[8];
    const float* q_b    = (const float*)d_in[9];
    const float* k_w    = (const float*)d_in[10];
    const float* k_b    = (const float*)d_in[11];
    const float* v_w    = (const float*)d_in[12];
    const float* v_b    = (const float*)d_in[13];
    const float* gamma  = (const float*)d_in[14];
    float* ws  = (float*)d_ws;
    float* out = (float*)d_out;

    conv_mod<<<dim3(8, 32, 4), 256, 0, stream>>>(x, conv_w, conv_b, style,
                                                 ss_w, ss_b, sb_w, sb_b, ws + OFF_H);
    qkv_kernel<<<dim3(160, 4), 256, 0, stream>>>(ws, q_w, q_b, k_w, k_b, v_w, v_b, gamma);
    attn_kernel<<<dim3(64, 4), 256, 0, stream>>>(ws, gamma);
    inorm_lrelu<<<512, 256, 0, stream>>>(ws, gamma, out);
}

// Round 5
// 186.085 us; speedup vs baseline: 6.4605x; 1.5940x over previous
//
#include <hip/hip_runtime.h>
#include <hip/hip_bf16.h>
#include <math.h>

// Problem constants (B,C_IN,C_OUT,STYLE,H,W = 4,128,128,512,64,64)
#define NN 4096
#define EPSV 1e-5f

// ---- workspace layout (float offsets) ----
static constexpr size_t OFF_H  = 1024;                          // [4*128*4096]
static constexpr size_t OFF_Q  = OFF_H + (size_t)4*128*4096;    // [4*16*4096]
static constexpr size_t OFF_K  = OFF_Q + (size_t)4*16*4096;
static constexpr size_t OFF_V  = OFF_K + (size_t)4*16*4096;     // [4*128*4096]
static constexpr size_t OFF_AO = OFF_V + (size_t)4*128*4096;    // [4*128*4096]

// DPP lane shifts across the full 64-lane wave. old=0 => out-of-range lanes
// read 0 under EITHER bound_ctrl polarity -> free zero padding at col -1/64.
__device__ __forceinline__ float dpp_shr1(float v) {   // lane l <- lane l-1
    return __int_as_float(__builtin_amdgcn_update_dpp(
        0, __float_as_int(v), 0x138 /*WAVE_SHR1*/, 0xf, 0xf, true));
}
__device__ __forceinline__ float dpp_shl1(float v) {   // lane l <- lane l+1
    return __int_as_float(__builtin_amdgcn_update_dpp(
        0, __float_as_int(v), 0x130 /*WAVE_SHL1*/, 0xf, 0xf, true));
}

// ---------------------------------------------------------------------------
// conv3x3 (pad 1) + bias + AdaIN modulation (style GEMV fused) -> h in ws.
// NO LDS, NO BARRIERS. Lane = column (64 cols), wave = 2 output channels,
// block = 4 waves x 2 co = 8 co, tile = 4 output rows.
// Grid (16 row-tiles, 16 co-groups, 4 b) = 1024 blocks = 4/CU, 4 waves/SIMD.
// x taps: 6 input rows/ci in registers (prefetched 1 ci ahead, coalesced,
// L2-resident); +-1 col neighbors via DPP wave shifts (VALU, zero-padded).
// weights: wave-uniform addresses (readfirstlane) -> s_load, ping-pong
// prefetched 1 ci ahead on the scalar pipe.
// ---------------------------------------------------------------------------
__global__ __launch_bounds__(256)
void conv_mod(const float* __restrict__ x,
              const float* __restrict__ conv_w,
              const float* __restrict__ conv_b,
              const float* __restrict__ style,
              const float* __restrict__ ss_w, const float* __restrict__ ss_b,
              const float* __restrict__ sb_w, const float* __restrict__ sb_b,
              float* __restrict__ hout) {
    const int b    = blockIdx.z;
    const int co0  = blockIdx.y * 8;
    const int ty0  = blockIdx.x * 4;
    const int t    = threadIdx.x;
    const int lane = t & 63;
    const int wv   = __builtin_amdgcn_readfirstlane(t >> 6);   // wave id (SGPR)
    const int coa  = co0 + 2 * wv;
    const int cob  = coa + 1;

    // ---- fused style GEMV: 4 dot-512 per wave (scale/bias for coa, cob) ----
    float dsA = 0.f, dsB = 0.f, dbA = 0.f, dbB = 0.f;
    {
        const float* st  = style + (size_t)b * 512;
        const float* wsa = ss_w + (size_t)coa * 512;
        const float* wsb = ss_w + (size_t)cob * 512;
        const float* wba = sb_w + (size_t)coa * 512;
        const float* wbb = sb_w + (size_t)cob * 512;
        for (int e = lane; e < 512; e += 64) {
            const float sv = st[e];
            dsA = fmaf(sv, wsa[e], dsA);
            dsB = fmaf(sv, wsb[e], dsB);
            dbA = fmaf(sv, wba[e], dbA);
            dbB = fmaf(sv, wbb[e], dbB);
        }
        #pragma unroll
        for (int off = 32; off; off >>= 1) {   // butterfly: sum lands in all lanes
            dsA += __shfl_xor(dsA, off);
            dsB += __shfl_xor(dsB, off);
            dbA += __shfl_xor(dbA, off);
            dbB += __shfl_xor(dbB, off);
        }
    }

    // ---- x row pointers (clamped; rows 0/5 masked when outside image) ----
    const float* xb = x + (size_t)b * 128 * NN;
    const float* xp[6];
    #pragma unroll
    for (int r = 0; r < 6; ++r) {
        int gy = ty0 + r - 1;
        int gyc = gy < 0 ? 0 : (gy > 63 ? 63 : gy);
        xp[r] = xb + gyc * 64 + lane;
    }
    const bool ok0 = (ty0 > 0);
    const bool ok5 = (ty0 < 60);

    // ---- weight base pointers (uniform -> scalar loads) ----
    const float* wpa = conv_w + (size_t)coa * 1152;
    const float* wpb = conv_w + (size_t)cob * 1152;

    float vA[6], vB[6];
    float waA[9], wbA[9], waB[9], wbB[9];
    float acc[4][2];
    #pragma unroll
    for (int o = 0; o < 4; ++o) { acc[o][0] = 0.f; acc[o][1] = 0.f; }

    // per-ci compute: 12 valid (r,ky) pairs, 72 FMA, 12 DPP
    auto conv_rows = [&](const float (&v)[6], const float (&wa)[9],
                         const float (&wb)[9]) {
        #pragma unroll
        for (int r = 0; r < 6; ++r) {
            const float m  = v[r];
            const float lf = dpp_shr1(m);
            const float rg = dpp_shl1(m);
            #pragma unroll
            for (int ky = 0; ky < 3; ++ky) {
                const int o = r - ky;
                if (o < 0 || o > 3) continue;
                acc[o][0] = fmaf(lf, wa[ky*3+0],
                            fmaf(m,  wa[ky*3+1],
                            fmaf(rg, wa[ky*3+2], acc[o][0])));
                acc[o][1] = fmaf(lf, wb[ky*3+0],
                            fmaf(m,  wb[ky*3+1],
                            fmaf(rg, wb[ky*3+2], acc[o][1])));
            }
        }
    };
    auto ldw = [](float (&w)[9], const float* p) {
        #pragma unroll
        for (int k = 0; k < 9; ++k) w[k] = p[k];
    };
    auto ldx = [&](float (&v)[6], int ci) {
        const size_t off = (size_t)ci * NN;
        #pragma unroll
        for (int r = 0; r < 6; ++r) v[r] = xp[r][off];
        if (!ok0) v[0] = 0.f;
        if (!ok5) v[5] = 0.f;
    };

    // prologue: ci = 0
    ldw(waA, wpa); ldw(wbA, wpb);
    ldx(vA, 0);

    for (int c = 0; c < 128; c += 2) {
        // prefetch ci = c+1 (scalar weights + vector x rows)
        ldw(waB, wpa + (c + 1) * 9);
        ldw(wbB, wpb + (c + 1) * 9);
        ldx(vB, c + 1);
        conv_rows(vA, waA, wbA);
        if (c + 2 < 128) {
            ldw(waA, wpa + (c + 2) * 9);
            ldw(wbA, wpb + (c + 2) * 9);
            ldx(vA, c + 2);
        }
        conv_rows(vB, waB, wbB);
    }

    // ---- epilogue: bias + modulation, coalesced b32 stores ----
    const float scA = 1.f + (dsA + ss_b[coa]);
    const float scB = 1.f + (dsB + ss_b[cob]);
    const float biA = dbA + sb_b[coa];
    const float biB = dbB + sb_b[cob];
    const float cbA = conv_b[coa];
    const float cbB = conv_b[cob];
    float* ha = hout + (size_t)(b * 128 + coa) * NN;
    float* hb = hout + (size_t)(b * 128 + cob) * NN;
    #pragma unroll
    for (int o = 0; o < 4; ++o) {
        const int px = (ty0 + o) * 64 + lane;
        ha[px] = (acc[o][0] + cbA) * scA + biA;
        hb[px] = (acc[o][1] + cbB) * scB + biB;
    }
}

// ---------------------------------------------------------------------------
// qkv (runs only if gamma != 0): q/k/v 1x1 convs from h.
// ---------------------------------------------------------------------------
__global__ __launch_bounds__(256)
void qkv_kernel(float* __restrict__ ws,
                const float* __restrict__ qw, const float* __restrict__ qb,
                const float* __restrict__ kw, const float* __restrict__ kb,
                const float* __restrict__ vw, const float* __restrict__ vb,
                const float* __restrict__ gamma) {
    if (gamma[0] == 0.f) return;
    const int b  = blockIdx.y;
    const int oc = blockIdx.x;   // 0..159: 16 q, 16 k, 128 v
    const float* wrow; float bias; float* dst;
    if (oc < 16)      { wrow = qw + (size_t)oc * 128;        bias = qb[oc];
                        dst = ws + OFF_Q + (size_t)(b * 16 + oc) * NN; }
    else if (oc < 32) { int c = oc - 16; wrow = kw + (size_t)c * 128; bias = kb[c];
                        dst = ws + OFF_K + (size_t)(b * 16 + c) * NN; }
    else              { int c = oc - 32; wrow = vw + (size_t)c * 128; bias = vb[c];
                        dst = ws + OFF_V + (size_t)(b * 128 + c) * NN; }
    const float* hb = ws + OFF_H + (size_t)b * 128 * NN;
    for (int n = threadIdx.x; n < NN; n += 256) {
        float a = bias;
        for (int ci = 0; ci < 128; ++ci) a += hb[(size_t)ci * NN + n] * wrow[ci];
        dst[n] = a;
    }
}

// ---------------------------------------------------------------------------
// attn (runs only if gamma != 0): flash-style, 64 queries per block.
// ---------------------------------------------------------------------------
__global__ __launch_bounds__(256)
void attn_kernel(float* __restrict__ ws, const float* __restrict__ gamma) {
    if (gamma[0] == 0.f) return;
    const int b  = blockIdx.y;
    const int n0 = blockIdx.x * 64;
    const int t  = threadIdx.x;

    __shared__ float q_s[16][64];
    __shared__ float k_s[16][64];
    __shared__ float v_s[64][129];
    __shared__ float p_s[64][65];
    __shared__ float m_run[64], l_run[64], sc_s[64];

    const float* qp = ws + OFF_Q + (size_t)b * 16 * NN;
    const float* kp = ws + OFF_K + (size_t)b * 16 * NN;
    const float* vp = ws + OFF_V + (size_t)b * 128 * NN;

    for (int idx = t; idx < 16 * 64; idx += 256) {
        int cq = idx >> 6, j = idx & 63;
        q_s[cq][j] = qp[(size_t)cq * NN + n0 + j];
    }
    if (t < 64) { m_run[t] = -1e30f; l_run[t] = 0.f; }

    const int n  = t & 63;
    const int cg = t >> 6;
    float acc[32];
    #pragma unroll
    for (int i = 0; i < 32; ++i) acc[i] = 0.f;
    __syncthreads();

    for (int mt = 0; mt < 64; ++mt) {
        const int m0 = mt * 64;
        for (int idx = t; idx < 16 * 64; idx += 256) {
            int cq = idx >> 6, j = idx & 63;
            k_s[cq][j] = kp[(size_t)cq * NN + m0 + j];
        }
        for (int idx = t; idx < 128 * 64; idx += 256) {
            int c = idx >> 6, j = idx & 63;
            v_s[j][c] = vp[(size_t)c * NN + m0 + j];
        }
        __syncthreads();
        {
            const int nn2   = t & 63;
            const int mbase = (t >> 6) * 16;
            for (int mi = 0; mi < 16; ++mi) {
                const int mm = mbase + mi;
                float s = 0.f;
                #pragma unroll
                for (int cq = 0; cq < 16; ++cq) s += q_s[cq][nn2] * k_s[cq][mm];
                p_s[nn2][mm] = s;
            }
        }
        __syncthreads();
        if (t < 64) {
            float mold = m_run[t];
            float mx = mold;
            for (int mm = 0; mm < 64; ++mm) mx = fmaxf(mx, p_s[t][mm]);
            float sc = expf(mold - mx);
            float rs = 0.f;
            for (int mm = 0; mm < 64; ++mm) {
                float p = expf(p_s[t][mm] - mx);
                p_s[t][mm] = p;
                rs += p;
            }
            l_run[t] = l_run[t] * sc + rs;
            m_run[t] = mx;
            sc_s[t]  = sc;
        }
        __syncthreads();
        {
            const float sc = sc_s[n];
            #pragma unroll
            for (int i = 0; i < 32; ++i) acc[i] *= sc;
            for (int mm = 0; mm < 64; ++mm) {
                const float p = p_s[n][mm];
                #pragma unroll
                for (int i = 0; i < 32; ++i) acc[i] += p * v_s[mm][cg * 32 + i];
            }
        }
        __syncthreads();
    }

    const float inv = 1.f / l_run[n];
    float* ao = ws + OFF_AO + (size_t)b * 128 * NN;
    for (int i = 0; i < 32; ++i)
        ao[(size_t)(cg * 32 + i) * NN + n0 + n] = acc[i] * inv;
}

// ---------------------------------------------------------------------------
// h2 = gamma*attn_out + h; InstanceNorm (biased var, eps=1e-5); LeakyReLU.
// ---------------------------------------------------------------------------
__global__ __launch_bounds__(256)
void inorm_lrelu(const float* __restrict__ ws,
                 const float* __restrict__ gamma,
                 float* __restrict__ out) {
    const int bc = blockIdx.x;      // b*128 + c
    const int t  = threadIdx.x;
    const float g = gamma[0];

    const float4* hp = (const float4*)(ws + OFF_H  + (size_t)bc * NN);
    const float4* ap = (const float4*)(ws + OFF_AO + (size_t)bc * NN);

    float4 v[4];
    #pragma unroll
    for (int i = 0; i < 4; ++i) {
        float4 hv = hp[t + 256 * i];
        if (g != 0.f) {
            float4 av = ap[t + 256 * i];
            hv.x += g * av.x; hv.y += g * av.y; hv.z += g * av.z; hv.w += g * av.w;
        }
        v[i] = hv;
    }

    float s1 = 0.f, s2 = 0.f;
    #pragma unroll
    for (int i = 0; i < 4; ++i) {
        s1 += v[i].x + v[i].y + v[i].z + v[i].w;
        s2 += v[i].x * v[i].x + v[i].y * v[i].y + v[i].z * v[i].z + v[i].w * v[i].w;
    }
    #pragma unroll
    for (int off = 32; off; off >>= 1) {
        s1 += __shfl_xor(s1, off);
        s2 += __shfl_xor(s2, off);
    }
    __shared__ float r1[4], r2[4];
    if ((t & 63) == 0) { r1[t >> 6] = s1; r2[t >> 6] = s2; }
    __syncthreads();
    const float S1 = r1[0] + r1[1] + r1[2] + r1[3];
    const float S2 = r2[0] + r2[1] + r2[2] + r2[3];
    const float mu  = S1 * (1.f / 4096.f);
    const float var = S2 * (1.f / 4096.f) - mu * mu;
    const float rs  = 1.f / sqrtf(var + EPSV);

    float4* op = (float4*)out + (size_t)bc * (NN / 4);
    #pragma unroll
    for (int i = 0; i < 4; ++i) {
        float4 o;
        o.x = (v[i].x - mu) * rs; o.x = o.x >= 0.f ? o.x : 0.2f * o.x;
        o.y = (v[i].y - mu) * rs; o.y = o.y >= 0.f ? o.y : 0.2f * o.y;
        o.z = (v[i].z - mu) * rs; o.z = o.z >= 0.f ? o.z : 0.2f * o.z;
        o.w = (v[i].w - mu) * rs; o.w = o.w >= 0.f ? o.w : 0.2f * o.w;
        op[t + 256 * i] = o;
    }
}

// ---------------------------------------------------------------------------
extern "C" void kernel_launch(void* const* d_in, const int* in_sizes, int n_in,
                              void* d_out, int out_size, void* d_ws, size_t ws_size,
                              hipStream_t stream) {
    const float* x      = (const float*)d_in[0];
    const float* style  = (const float*)d_in[1];
    const float* conv_w = (const float*)d_in[2];
    const float* conv_b = (const float*)d_in[3];
    const float* ss_w   = (const float*)d_in[4];
    const float* ss_b   = (const float*)d_in[5];
    const float* sb_w   = (const float*)d_in[6];
    const float* sb_b   = (const float*)d_in[7];
    const float* q_w    = (const float*)d_in[8];
    const float* q_b    = (const float*)d_in[9];
    const float* k_w    = (const float*)d_in[10];
    const float* k_b    = (const float*)d_in[11];
    const float* v_w    = (const float*)d_in[12];
    const float* v_b    = (const float*)d_in[13];
    const float* gamma  = (const float*)d_in[14];
    float* ws  = (float*)d_ws;
    float* out = (float*)d_out;

    conv_mod<<<dim3(16, 16, 4), 256, 0, stream>>>(x, conv_w, conv_b, style,
                                                  ss_w, ss_b, sb_w, sb_b, ws + OFF_H);
    qkv_kernel<<<dim3(160, 4), 256, 0, stream>>>(ws, q_w, q_b, k_w, k_b, v_w, v_b, gamma);
    attn_kernel<<<dim3(64, 4), 256, 0, stream>>>(ws, gamma);
    inorm_lrelu<<<512, 256, 0, stream>>>(ws, gamma, out);
}

// Round 6
// 152.572 us; speedup vs baseline: 7.8796x; 1.2197x over previous
//
#include <hip/hip_runtime.h>
#include <hip/hip_bf16.h>
#include <math.h>

// Problem constants (B,C_IN,C_OUT,STYLE,H,W = 4,128,128,512,64,64)
#define NN 4096
#define EPSV 1e-5f

typedef short short8 __attribute__((ext_vector_type(8)));   // 8 bf16 bit-patterns
typedef float f32x4 __attribute__((ext_vector_type(4)));

// ---- workspace layout (float offsets) ----
static constexpr size_t OFF_SCALE = 0;                            // [4*128]
static constexpr size_t OFF_BIAS  = 512;                          // [4*128]
static constexpr size_t OFF_H     = 1024;                         // [4*128*4096] f32
static constexpr size_t OFF_Q     = OFF_H  + (size_t)4*128*4096;  // [4*16*4096]
static constexpr size_t OFF_K     = OFF_Q  + (size_t)4*16*4096;
static constexpr size_t OFF_V     = OFF_K  + (size_t)4*16*4096;   // [4*128*4096]
static constexpr size_t OFF_AO    = OFF_V  + (size_t)4*128*4096;  // [4*128*4096]
// bf16 regions (ushort), sizes given in float units (/2)
static constexpr size_t OFF_XHI   = OFF_AO + (size_t)4*128*4096;            // 4*66*66*128 us
static constexpr size_t OFF_XLO   = OFF_XHI + (size_t)4*66*66*128/2;
static constexpr size_t OFF_WPK   = OFF_XLO + (size_t)4*66*66*128/2;        // 2*4*9*8*64*8 us

__device__ __forceinline__ unsigned short f2bf(float f) {   // RNE truncate to bf16 bits
    unsigned u = __float_as_uint(f);
    unsigned r = u + 0x7FFFu + ((u >> 16) & 1u);
    return (unsigned short)(r >> 16);
}
__device__ __forceinline__ float bf2f(unsigned short h) {
    return __uint_as_float(((unsigned)h) << 16);
}

// ---------------------------------------------------------------------------
// k1: scale[b,c] = style[b]·ss_w[c] + ss_b[c]; bias likewise. 1 wave / (b,c).
// ---------------------------------------------------------------------------
__global__ __launch_bounds__(64)
void style_affine(const float* __restrict__ style,
                  const float* __restrict__ ss_w, const float* __restrict__ ss_b,
                  const float* __restrict__ sb_w, const float* __restrict__ sb_b,
                  float* __restrict__ ws) {
    int bc = blockIdx.x;            // b*128 + c
    int b = bc >> 7, c = bc & 127;
    int lane = threadIdx.x;
    const float* st = style + (size_t)b * 512;
    float s1 = 0.f, s2 = 0.f;
    for (int e = lane; e < 512; e += 64) {
        float sv = st[e];
        s1 = fmaf(sv, ss_w[(size_t)c * 512 + e], s1);
        s2 = fmaf(sv, sb_w[(size_t)c * 512 + e], s2);
    }
    #pragma unroll
    for (int off = 32; off; off >>= 1) {
        s1 += __shfl_xor(s1, off);
        s2 += __shfl_xor(s2, off);
    }
    if (lane == 0) {
        ws[OFF_SCALE + bc] = s1 + ss_b[c];
        ws[OFF_BIAS  + bc] = s2 + sb_b[c];
    }
}

// ---------------------------------------------------------------------------
// k2: transpose + zero-pad + bf16 hi/lo split of x:
//   xT[b][yp 0..65][xp 0..65][ci 0..127], valid image at (yp,xp)=(y+1,x+1).
// Grid (66 yp, 4 b) x 256 thr. Pad rows/cols zero-filled EVERY launch (ws is
// re-poisoned). LDS transpose for coalescing on both sides.
// ---------------------------------------------------------------------------
__global__ __launch_bounds__(256)
void xpose(const float* __restrict__ x, float* __restrict__ ws) {
    const int yp = blockIdx.x;      // 0..65
    const int b  = blockIdx.y;
    const int t  = threadIdx.x;
    unsigned short* xh = (unsigned short*)(ws + OFF_XHI) + ((size_t)b * 66 + yp) * 66 * 128;
    unsigned short* xl = (unsigned short*)(ws + OFF_XLO) + ((size_t)b * 66 + yp) * 66 * 128;
    if (yp == 0 || yp == 65) {      // full zero rows
        for (int i = t; i < 66 * 128; i += 256) { xh[i] = 0; xl[i] = 0; }
        return;
    }
    const int y = yp - 1;
    __shared__ float s[64][129];
    const float* src = x + (size_t)b * 128 * NN + y * 64;
    for (int j = t; j < 8192; j += 256) {       // coalesced [ci][xx] read
        int ci = j >> 6, xx = j & 63;
        s[xx][ci] = src[(size_t)ci * NN + xx];
    }
    if (t < 128) {                  // zero xp = 0 and xp = 65 edges
        xh[t] = 0; xl[t] = 0;
        xh[65 * 128 + t] = 0; xl[65 * 128 + t] = 0;
    }
    __syncthreads();
    const int xx = t >> 2, cig = t & 3;         // 32 ci per thread
    unsigned short hi[32], lo[32];
    #pragma unroll
    for (int i = 0; i < 32; ++i) {
        float f = s[xx][cig * 32 + i];
        unsigned short h = f2bf(f);
        hi[i] = h;
        lo[i] = f2bf(f - bf2f(h));
    }
    unsigned short* dh = xh + (size_t)(xx + 1) * 128 + cig * 32;
    unsigned short* dl = xl + (size_t)(xx + 1) * 128 + cig * 32;
    #pragma unroll
    for (int k = 0; k < 4; ++k) {
        short8 vh, vl;
        #pragma unroll
        for (int j = 0; j < 8; ++j) { vh[j] = (short)hi[k*8+j]; vl[j] = (short)lo[k*8+j]; }
        *(short8*)(dh + k * 8) = vh;
        *(short8*)(dl + k * 8) = vl;
    }
}

// ---------------------------------------------------------------------------
// k3: pre-pack conv weights into MFMA B-fragment order (hi and lo parts):
//   wpack[((part*4+kb)*9+tap)*8+cog][lane 0..63][j 0..7]  (ushort)
//   lane l supplies B[k=(l>>4)*8+j][n=l&15] = w[co=cog*16+(l&15)][ci=kb*32+(l>>4)*8+j]
// Grid 576 x 64 thr.
// ---------------------------------------------------------------------------
__global__ __launch_bounds__(64)
void wpack_kernel(const float* __restrict__ conv_w, float* __restrict__ ws) {
    const int id = blockIdx.x;           // ((part*4+kb)*9+tap)*8+cog
    const int l  = threadIdx.x;
    const int cog = id & 7;
    const int q   = id >> 3;
    const int tap = q % 9;
    const int p2  = q / 9;
    const int kb  = p2 & 3;
    const int part= p2 >> 2;
    const int co  = cog * 16 + (l & 15);
    const int ci0 = kb * 32 + (l >> 4) * 8;
    short8 v;
    #pragma unroll
    for (int j = 0; j < 8; ++j) {
        float f = conv_w[(size_t)co * 1152 + (size_t)(ci0 + j) * 9 + tap];
        unsigned short h = f2bf(f);
        v[j] = (short)(part == 0 ? h : f2bf(f - bf2f(h)));
    }
    unsigned short* wp = (unsigned short*)(ws + OFF_WPK);
    *(short8*)(wp + ((size_t)id * 64 + l) * 8) = v;
}

// ---------------------------------------------------------------------------
// k4: MFMA conv3x3 + bias + AdaIN modulation -> h.   NO LDS, NO BARRIERS.
// C[m=x, n=co] = sum_k A[x,k]·B[k,co], K = (kb 0..3)x(tap 0..8) blocks of 32 ci.
// Split-bf16: acc += Xhi·Whi + Xlo·Whi + Xhi·Wlo.
// Block: M=64 (one image row y), N=64 co; 4 waves = 2Mx2N; wave: 2x2 frags.
// Grid (64 y, 2 co-half, 4 b) = 512 blocks = 2/CU.
// A-frags: global dwordx4 from xT (L1-resident per kb). B-frags: contiguous
// 1KB/wave from wpack (L2-broadcast).
// ---------------------------------------------------------------------------
__global__ __launch_bounds__(256)
void mfma_conv(float* __restrict__ ws, const float* __restrict__ conv_b) {
    const int y   = blockIdx.x;
    const int coh = blockIdx.y;
    const int b   = blockIdx.z;
    const int t   = threadIdx.x;
    const int l   = t & 63;
    const int wv  = t >> 6;
    const int wm  = wv & 1;          // M-half
    const int wn  = wv >> 1;         // N-half
    const int x0  = wm * 32;
    const int cobase = coh * 64 + wn * 32;
    const int lr = l & 15, lg = l >> 4;

    const unsigned short* xh = (const unsigned short*)(ws + OFF_XHI) + (size_t)b * 66 * 66 * 128;
    const unsigned short* xl = (const unsigned short*)(ws + OFF_XLO) + (size_t)b * 66 * 66 * 128;
    const unsigned short* wp = (const unsigned short*)(ws + OFF_WPK);

    const size_t aL0 = (size_t)(x0 + lr) * 128 + (size_t)lg * 8;  // ushort units
    const size_t aL1 = aL0 + 16 * 128;
    const int cog0 = coh * 4 + wn * 2;                            // co-frag index /16

    f32x4 acc00 = {0,0,0,0}, acc01 = {0,0,0,0};
    f32x4 acc10 = {0,0,0,0}, acc11 = {0,0,0,0};

    for (int kb = 0; kb < 4; ++kb) {
        #pragma unroll
        for (int ky = 0; ky < 3; ++ky) {
            #pragma unroll
            for (int kx = 0; kx < 3; ++kx) {
                const int tap = ky * 3 + kx;
                const size_t su = ((size_t)(y + ky) * 66 + kx) * 128 + (size_t)kb * 32;
                short8 ah0 = *(const short8*)(xh + su + aL0);
                short8 ah1 = *(const short8*)(xh + su + aL1);
                short8 al0 = *(const short8*)(xl + su + aL0);
                short8 al1 = *(const short8*)(xl + su + aL1);
                const size_t fh = ((size_t)(kb * 9 + tap) * 8 + cog0) * 512 + (size_t)l * 8;
                const size_t fl = ((size_t)((4 + kb) * 9 + tap) * 8 + cog0) * 512 + (size_t)l * 8;
                short8 bh0 = *(const short8*)(wp + fh);
                short8 bh1 = *(const short8*)(wp + fh + 512);
                short8 bl0 = *(const short8*)(wp + fl);
                short8 bl1 = *(const short8*)(wp + fl + 512);
                acc00 = __builtin_amdgcn_mfma_f32_16x16x32_bf16(ah0, bh0, acc00, 0,0,0);
                acc00 = __builtin_amdgcn_mfma_f32_16x16x32_bf16(al0, bh0, acc00, 0,0,0);
                acc00 = __builtin_amdgcn_mfma_f32_16x16x32_bf16(ah0, bl0, acc00, 0,0,0);
                acc01 = __builtin_amdgcn_mfma_f32_16x16x32_bf16(ah0, bh1, acc01, 0,0,0);
                acc01 = __builtin_amdgcn_mfma_f32_16x16x32_bf16(al0, bh1, acc01, 0,0,0);
                acc01 = __builtin_amdgcn_mfma_f32_16x16x32_bf16(ah0, bl1, acc01, 0,0,0);
                acc10 = __builtin_amdgcn_mfma_f32_16x16x32_bf16(ah1, bh0, acc10, 0,0,0);
                acc10 = __builtin_amdgcn_mfma_f32_16x16x32_bf16(al1, bh0, acc10, 0,0,0);
                acc10 = __builtin_amdgcn_mfma_f32_16x16x32_bf16(ah1, bl0, acc10, 0,0,0);
                acc11 = __builtin_amdgcn_mfma_f32_16x16x32_bf16(ah1, bh1, acc11, 0,0,0);
                acc11 = __builtin_amdgcn_mfma_f32_16x16x32_bf16(al1, bh1, acc11, 0,0,0);
                acc11 = __builtin_amdgcn_mfma_f32_16x16x32_bf16(ah1, bl1, acc11, 0,0,0);
            }
        }
    }

    // ---- epilogue: C/D layout col=lane&15 (co), row=(lane>>4)*4+reg (x) ----
    const float* scp = ws + OFF_SCALE + b * 128;
    const float* bip = ws + OFF_BIAS  + b * 128;
    float* hout = ws + OFF_H;
    #pragma unroll
    for (int nf = 0; nf < 2; ++nf) {
        const int co = cobase + nf * 16 + lr;
        const float sc = 1.f + scp[co];
        const float bi = bip[co];
        const float cb = conv_b[co];
        #pragma unroll
        for (int mf = 0; mf < 2; ++mf) {
            f32x4 a = (nf == 0) ? (mf == 0 ? acc00 : acc10)
                                : (mf == 0 ? acc01 : acc11);
            float4 o;
            o.x = (a[0] + cb) * sc + bi;
            o.y = (a[1] + cb) * sc + bi;
            o.z = (a[2] + cb) * sc + bi;
            o.w = (a[3] + cb) * sc + bi;
            const int xo = x0 + mf * 16 + lg * 4;
            *(float4*)(hout + (size_t)(b * 128 + co) * NN + y * 64 + xo) = o;
        }
    }
}

// ---------------------------------------------------------------------------
// qkv (runs only if gamma != 0): q/k/v 1x1 convs from h.
// ---------------------------------------------------------------------------
__global__ __launch_bounds__(256)
void qkv_kernel(float* __restrict__ ws,
                const float* __restrict__ qw, const float* __restrict__ qb,
                const float* __restrict__ kw, const float* __restrict__ kb,
                const float* __restrict__ vw, const float* __restrict__ vb,
                const float* __restrict__ gamma) {
    if (gamma[0] == 0.f) return;
    const int b  = blockIdx.y;
    const int oc = blockIdx.x;   // 0..159: 16 q, 16 k, 128 v
    const float* wrow; float bias; float* dst;
    if (oc < 16)      { wrow = qw + (size_t)oc * 128;        bias = qb[oc];
                        dst = ws + OFF_Q + (size_t)(b * 16 + oc) * NN; }
    else if (oc < 32) { int c = oc - 16; wrow = kw + (size_t)c * 128; bias = kb[c];
                        dst = ws + OFF_K + (size_t)(b * 16 + c) * NN; }
    else              { int c = oc - 32; wrow = vw + (size_t)c * 128; bias = vb[c];
                        dst = ws + OFF_V + (size_t)(b * 128 + c) * NN; }
    const float* hb = ws + OFF_H + (size_t)b * 128 * NN;
    for (int n = threadIdx.x; n < NN; n += 256) {
        float a = bias;
        for (int ci = 0; ci < 128; ++ci) a += hb[(size_t)ci * NN + n] * wrow[ci];
        dst[n] = a;
    }
}

// ---------------------------------------------------------------------------
// attn (runs only if gamma != 0): flash-style, 64 queries per block.
// ---------------------------------------------------------------------------
__global__ __launch_bounds__(256)
void attn_kernel(float* __restrict__ ws, const float* __restrict__ gamma) {
    if (gamma[0] == 0.f) return;
    const int b  = blockIdx.y;
    const int n0 = blockIdx.x * 64;
    const int t  = threadIdx.x;

    __shared__ float q_s[16][64];
    __shared__ float k_s[16][64];
    __shared__ float v_s[64][129];
    __shared__ float p_s[64][65];
    __shared__ float m_run[64], l_run[64], sc_s[64];

    const float* qp = ws + OFF_Q + (size_t)b * 16 * NN;
    const float* kp = ws + OFF_K + (size_t)b * 16 * NN;
    const float* vp = ws + OFF_V + (size_t)b * 128 * NN;

    for (int idx = t; idx < 16 * 64; idx += 256) {
        int cq = idx >> 6, j = idx & 63;
        q_s[cq][j] = qp[(size_t)cq * NN + n0 + j];
    }
    if (t < 64) { m_run[t] = -1e30f; l_run[t] = 0.f; }

    const int n  = t & 63;
    const int cg = t >> 6;
    float acc[32];
    #pragma unroll
    for (int i = 0; i < 32; ++i) acc[i] = 0.f;
    __syncthreads();

    for (int mt = 0; mt < 64; ++mt) {
        const int m0 = mt * 64;
        for (int idx = t; idx < 16 * 64; idx += 256) {
            int cq = idx >> 6, j = idx & 63;
            k_s[cq][j] = kp[(size_t)cq * NN + m0 + j];
        }
        for (int idx = t; idx < 128 * 64; idx += 256) {
            int c = idx >> 6, j = idx & 63;
            v_s[j][c] = vp[(size_t)c * NN + m0 + j];
        }
        __syncthreads();
        {
            const int nn2   = t & 63;
            const int mbase = (t >> 6) * 16;
            for (int mi = 0; mi < 16; ++mi) {
                const int mm = mbase + mi;
                float s = 0.f;
                #pragma unroll
                for (int cq = 0; cq < 16; ++cq) s += q_s[cq][nn2] * k_s[cq][mm];
                p_s[nn2][mm] = s;
            }
        }
        __syncthreads();
        if (t < 64) {
            float mold = m_run[t];
            float mx = mold;
            for (int mm = 0; mm < 64; ++mm) mx = fmaxf(mx, p_s[t][mm]);
            float sc = expf(mold - mx);
            float rs = 0.f;
            for (int mm = 0; mm < 64; ++mm) {
                float p = expf(p_s[t][mm] - mx);
                p_s[t][mm] = p;
                rs += p;
            }
            l_run[t] = l_run[t] * sc + rs;
            m_run[t] = mx;
            sc_s[t]  = sc;
        }
        __syncthreads();
        {
            const float sc = sc_s[n];
            #pragma unroll
            for (int i = 0; i < 32; ++i) acc[i] *= sc;
            for (int mm = 0; mm < 64; ++mm) {
                const float p = p_s[n][mm];
                #pragma unroll
                for (int i = 0; i < 32; ++i) acc[i] += p * v_s[mm][cg * 32 + i];
            }
        }
        __syncthreads();
    }

    const float inv = 1.f / l_run[n];
    float* ao = ws + OFF_AO + (size_t)b * 128 * NN;
    for (int i = 0; i < 32; ++i)
        ao[(size_t)(cg * 32 + i) * NN + n0 + n] = acc[i] * inv;
}

// ---------------------------------------------------------------------------
// h2 = gamma*attn_out + h; InstanceNorm (biased var, eps=1e-5); LeakyReLU.
// ---------------------------------------------------------------------------
__global__ __launch_bounds__(256)
void inorm_lrelu(const float* __restrict__ ws,
                 const float* __restrict__ gamma,
                 float* __restrict__ out) {
    const int bc = blockIdx.x;      // b*128 + c
    const int t  = threadIdx.x;
    const float g = gamma[0];

    const float4* hp = (const float4*)(ws + OFF_H  + (size_t)bc * NN);
    const float4* ap = (const float4*)(ws + OFF_AO + (size_t)bc * NN);

    float4 v[4];
    #pragma unroll
    for (int i = 0; i < 4; ++i) {
        float4 hv = hp[t + 256 * i];
        if (g != 0.f) {
            float4 av = ap[t + 256 * i];
            hv.x += g * av.x; hv.y += g * av.y; hv.z += g * av.z; hv.w += g * av.w;
        }
        v[i] = hv;
    }

    float s1 = 0.f, s2 = 0.f;
    #pragma unroll
    for (int i = 0; i < 4; ++i) {
        s1 += v[i].x + v[i].y + v[i].z + v[i].w;
        s2 += v[i].x * v[i].x + v[i].y * v[i].y + v[i].z * v[i].z + v[i].w * v[i].w;
    }
    #pragma unroll
    for (int off = 32; off; off >>= 1) {
        s1 += __shfl_xor(s1, off);
        s2 += __shfl_xor(s2, off);
    }
    __shared__ float r1[4], r2[4];
    if ((t & 63) == 0) { r1[t >> 6] = s1; r2[t >> 6] = s2; }
    __syncthreads();
    const float S1 = r1[0] + r1[1] + r1[2] + r1[3];
    const float S2 = r2[0] + r2[1] + r2[2] + r2[3];
    const float mu  = S1 * (1.f / 4096.f);
    const float var = S2 * (1.f / 4096.f) - mu * mu;
    const float rs  = 1.f / sqrtf(var + EPSV);

    float4* op = (float4*)out + (size_t)bc * (NN / 4);
    #pragma unroll
    for (int i = 0; i < 4; ++i) {
        float4 o;
        o.x = (v[i].x - mu) * rs; o.x = o.x >= 0.f ? o.x : 0.2f * o.x;
        o.y = (v[i].y - mu) * rs; o.y = o.y >= 0.f ? o.y : 0.2f * o.y;
        o.z = (v[i].z - mu) * rs; o.z = o.z >= 0.f ? o.z : 0.2f * o.z;
        o.w = (v[i].w - mu) * rs; o.w = o.w >= 0.f ? o.w : 0.2f * o.w;
        op[t + 256 * i] = o;
    }
}

// ---------------------------------------------------------------------------
extern "C" void kernel_launch(void* const* d_in, const int* in_sizes, int n_in,
                              void* d_out, int out_size, void* d_ws, size_t ws_size,
                              hipStream_t stream) {
    const float* x      = (const float*)d_in[0];
    const float* style  = (const float*)d_in[1];
    const float* conv_w = (const float*)d_in[2];
    const float* conv_b = (const float*)d_in[3];
    const float* ss_w   = (const float*)d_in[4];
    const float* ss_b   = (const float*)d_in[5];
    const float* sb_w   = (const float*)d_in[6];
    const float* sb_b   = (const float*)d_in[7];
    const float* q_w    = (const float*)d_in[8];
    const float* q_b    = (const float*)d_in[9];
    const float* k_w    = (const float*)d_in[10];
    const float* k_b    = (const float*)d_in[11];
    const float* v_w    = (const float*)d_in[12];
    const float* v_b    = (const float*)d_in[13];
    const float* gamma  = (const float*)d_in[14];
    float* ws  = (float*)d_ws;
    float* out = (float*)d_out;

    style_affine<<<512, 64, 0, stream>>>(style, ss_w, ss_b, sb_w, sb_b, ws);
    xpose<<<dim3(66, 4), 256, 0, stream>>>(x, ws);
    wpack_kernel<<<576, 64, 0, stream>>>(conv_w, ws);
    mfma_conv<<<dim3(64, 2, 4), 256, 0, stream>>>(ws, conv_b);
    qkv_kernel<<<dim3(160, 4), 256, 0, stream>>>(ws, q_w, q_b, k_w, k_b, v_w, v_b, gamma);
    attn_kernel<<<dim3(64, 4), 256, 0, stream>>>(ws, gamma);
    inorm_lrelu<<<512, 256, 0, stream>>>(ws, gamma, out);
}

// Round 7
// 141.397 us; speedup vs baseline: 8.5023x; 1.0790x over previous
//
#include <hip/hip_runtime.h>
#include <hip/hip_bf16.h>
#include <math.h>

// Problem constants (B,C_IN,C_OUT,STYLE,H,W = 4,128,128,512,64,64)
#define NN 4096
#define EPSV 1e-5f

typedef short short8 __attribute__((ext_vector_type(8)));   // 8 bf16 bit-patterns
typedef float f32x4 __attribute__((ext_vector_type(4)));

// ---- workspace layout (float offsets) ----
static constexpr size_t OFF_SCALE = 0;                            // [4*128]
static constexpr size_t OFF_BIAS  = 512;                          // [4*128]
static constexpr size_t OFF_H     = 1024;                         // [4*128*4096] f32
static constexpr size_t OFF_Q     = OFF_H  + (size_t)4*128*4096;  // [4*16*4096]
static constexpr size_t OFF_K     = OFF_Q  + (size_t)4*16*4096;
static constexpr size_t OFF_V     = OFF_K  + (size_t)4*16*4096;   // [4*128*4096]
static constexpr size_t OFF_AO    = OFF_V  + (size_t)4*128*4096;  // [4*128*4096]
// bf16 regions (ushort), sizes given in float units (/2)
static constexpr size_t OFF_XHI   = OFF_AO + (size_t)4*128*4096;            // 4*66*66*128 us
static constexpr size_t OFF_XLO   = OFF_XHI + (size_t)4*66*66*128/2;
static constexpr size_t OFF_WPK   = OFF_XLO + (size_t)4*66*66*128/2;        // 2*4*9*8*64*8 us

__device__ __forceinline__ unsigned short f2bf(float f) {   // RNE to bf16 bits
    unsigned u = __float_as_uint(f);
    unsigned r = u + 0x7FFFu + ((u >> 16) & 1u);
    return (unsigned short)(r >> 16);
}
__device__ __forceinline__ float bf2f(unsigned short h) {
    return __uint_as_float(((unsigned)h) << 16);
}

// ---------------------------------------------------------------------------
// prep: ONE launch doing (a) x transpose+pad+bf16 split, (b) weight pack,
// (c) style GEMV. Role by blockIdx.x:
//   [0,528):   xpose half — yp=bi>>3, b=(bi&7)>>1, h=bi&1 (ci half)
//   [528,672): wpack — 4 ids per block
//   [672,800): style — 4 (b,c) rows per block
// ---------------------------------------------------------------------------
__global__ __launch_bounds__(256)
void prep(const float* __restrict__ x, const float* __restrict__ conv_w,
          const float* __restrict__ style,
          const float* __restrict__ ss_w, const float* __restrict__ ss_b,
          const float* __restrict__ sb_w, const float* __restrict__ sb_b,
          float* __restrict__ ws) {
    const int bi = blockIdx.x;
    const int t  = threadIdx.x;

    if (bi < 528) {
        // ---------------- xpose: (yp, b, ci-half) ----------------
        const int yp = bi >> 3;
        const int b  = (bi & 7) >> 1;
        const int h  = bi & 1;                 // ci in [h*64, h*64+64)
        unsigned short* xh = (unsigned short*)(ws + OFF_XHI) + ((size_t)b * 66 + yp) * 66 * 128;
        unsigned short* xl = (unsigned short*)(ws + OFF_XLO) + ((size_t)b * 66 + yp) * 66 * 128;
        const short8 z8 = {0,0,0,0,0,0,0,0};

        if (yp == 0 || yp == 65) {             // full zero row (this ci-half)
            for (int task = t; task < 1056; task += 256) {
                const int buf = task >= 528;
                const int tt  = task - 528 * buf;
                const int xp  = tt >> 3, g = tt & 7;
                unsigned short* p = (buf ? xl : xh) + (size_t)xp * 128 + h * 64 + g * 8;
                *(short8*)p = z8;
            }
            return;
        }
        const int y = yp - 1;
        __shared__ float s[64][65];
        const float* src = x + (size_t)b * 128 * NN + (size_t)h * 64 * NN + y * 64;
        for (int j = t; j < 4096; j += 256) {  // coalesced [ci][xx] read
            const int ci = j >> 6, xx = j & 63;
            s[xx][ci] = src[(size_t)ci * NN + xx];
        }
        if (t < 32) {                          // zero xp=0 / xp=65 edges
            const int buf = t >> 4, e = (t >> 3) & 1, g = t & 7;
            unsigned short* p = (buf ? xl : xh) + (size_t)e * 65 * 128 + h * 64 + g * 8;
            *(short8*)p = z8;
        }
        __syncthreads();
        #pragma unroll
        for (int rep = 0; rep < 2; ++rep) {
            const int task = t + rep * 256;    // 512 tasks: 64 xx * 8 groups
            const int xx = task >> 3, g = task & 7;
            short8 vh, vl;
            #pragma unroll
            for (int j = 0; j < 8; ++j) {
                const float f = s[xx][g * 8 + j];
                const unsigned short hh = f2bf(f);
                vh[j] = (short)hh;
                vl[j] = (short)f2bf(f - bf2f(hh));
            }
            const size_t o = (size_t)(xx + 1) * 128 + h * 64 + g * 8;
            *(short8*)(xh + o) = vh;
            *(short8*)(xl + o) = vl;
        }
    } else if (bi < 672) {
        // ---------------- wpack: B-fragment pre-pack ----------------
        const int id = (bi - 528) * 4 + (t >> 6);    // 0..575
        const int l  = t & 63;
        const int cog = id & 7;
        const int q   = id >> 3;
        const int tap = q % 9;
        const int p2  = q / 9;
        const int kb  = p2 & 3;
        const int part= p2 >> 2;
        const int co  = cog * 16 + (l & 15);
        const int ci0 = kb * 32 + (l >> 4) * 8;
        short8 v;
        #pragma unroll
        for (int j = 0; j < 8; ++j) {
            const float f = conv_w[(size_t)co * 1152 + (size_t)(ci0 + j) * 9 + tap];
            const unsigned short hh = f2bf(f);
            v[j] = (short)(part == 0 ? hh : f2bf(f - bf2f(hh)));
        }
        unsigned short* wp = (unsigned short*)(ws + OFF_WPK);
        *(short8*)(wp + ((size_t)id * 64 + l) * 8) = v;
    } else {
        // ---------------- style GEMV ----------------
        const int bc = (bi - 672) * 4 + (t >> 6);    // 0..511
        const int b = bc >> 7, c = bc & 127;
        const int lane = t & 63;
        const float* st = style + (size_t)b * 512;
        float s1 = 0.f, s2 = 0.f;
        for (int e = lane; e < 512; e += 64) {
            const float sv = st[e];
            s1 = fmaf(sv, ss_w[(size_t)c * 512 + e], s1);
            s2 = fmaf(sv, sb_w[(size_t)c * 512 + e], s2);
        }
        #pragma unroll
        for (int off = 32; off; off >>= 1) {
            s1 += __shfl_xor(s1, off);
            s2 += __shfl_xor(s2, off);
        }
        if (lane == 0) {
            ws[OFF_SCALE + bc] = s1 + ss_b[c];
            ws[OFF_BIAS  + bc] = s2 + sb_b[c];
        }
    }
}

// ---------------------------------------------------------------------------
// mfma_conv: conv3x3 + bias + AdaIN -> h.  NO LDS, NO BARRIERS.
// Split-bf16: acc += Xhi·Whi + Xlo·Whi + Xhi·Wlo over K = 36 stages (kb,tap).
// 3-deep software pipeline: named stages SA/SB/SC (static indexing), loads
// for stage s+3 issued right after stage s is consumed. Stage addressing is
// wave-uniform -> SALU/SGPR base; lane offsets fixed.
// Block: M=64 (row y) x N=64 co, 4 waves = 2Mx2N, wave = 2x2 frags.
// Grid (64 y, 2 coh, 4 b) = 512 blocks = 2/CU.
// ---------------------------------------------------------------------------
struct St { short8 ah0, ah1, al0, al1, bh0, bh1, bl0, bl1; };

__global__ __launch_bounds__(256, 2)
void mfma_conv(float* __restrict__ ws, const float* __restrict__ conv_b) {
    const int y   = blockIdx.x;
    const int coh = blockIdx.y;
    const int b   = blockIdx.z;
    const int t   = threadIdx.x;
    const int l   = t & 63;
    const int wv  = t >> 6;
    const int wm  = wv & 1;
    const int wn  = wv >> 1;
    const int x0  = wm * 32;
    const int cobase = coh * 64 + wn * 32;
    const int lr = l & 15, lg = l >> 4;

    const unsigned short* xh = (const unsigned short*)(ws + OFF_XHI) + (size_t)b * 66 * 66 * 128;
    const unsigned short* xl = (const unsigned short*)(ws + OFF_XLO) + (size_t)b * 66 * 66 * 128;
    const unsigned short* wp = (const unsigned short*)(ws + OFF_WPK);

    const size_t aL0 = (size_t)(x0 + lr) * 128 + (size_t)lg * 8;  // ushort units
    const size_t aL1 = aL0 + 16 * 128;
    const int cog0 = coh * 4 + wn * 2;

    f32x4 acc00 = {0,0,0,0}, acc01 = {0,0,0,0};
    f32x4 acc10 = {0,0,0,0}, acc11 = {0,0,0,0};

    auto load_st = [&](St& S, int s) {
        const int kb  = s / 9;           // uniform -> scalar pipe
        const int tap = s - 9 * kb;
        const int ky  = tap / 3;
        const int kx  = tap - 3 * ky;
        const size_t su = ((size_t)(y + ky) * 66 + kx) * 128 + (size_t)kb * 32;
        const unsigned short* ph = xh + su;
        const unsigned short* pl = xl + su;
        S.ah0 = *(const short8*)(ph + aL0);
        S.ah1 = *(const short8*)(ph + aL1);
        S.al0 = *(const short8*)(pl + aL0);
        S.al1 = *(const short8*)(pl + aL1);
        const unsigned short* pbh = wp + ((size_t)(kb * 9 + tap) * 8 + cog0) * 512 + (size_t)l * 8;
        const unsigned short* pbl = pbh + (size_t)36 * 8 * 512;   // part=1 region
        S.bh0 = *(const short8*)pbh;
        S.bh1 = *(const short8*)(pbh + 512);
        S.bl0 = *(const short8*)pbl;
        S.bl1 = *(const short8*)(pbl + 512);
    };
    auto do_mfma = [&](const St& S) {
        acc00 = __builtin_amdgcn_mfma_f32_16x16x32_bf16(S.ah0, S.bh0, acc00, 0,0,0);
        acc01 = __builtin_amdgcn_mfma_f32_16x16x32_bf16(S.ah0, S.bh1, acc01, 0,0,0);
        acc10 = __builtin_amdgcn_mfma_f32_16x16x32_bf16(S.ah1, S.bh0, acc10, 0,0,0);
        acc11 = __builtin_amdgcn_mfma_f32_16x16x32_bf16(S.ah1, S.bh1, acc11, 0,0,0);
        acc00 = __builtin_amdgcn_mfma_f32_16x16x32_bf16(S.al0, S.bh0, acc00, 0,0,0);
        acc01 = __builtin_amdgcn_mfma_f32_16x16x32_bf16(S.al0, S.bh1, acc01, 0,0,0);
        acc10 = __builtin_amdgcn_mfma_f32_16x16x32_bf16(S.al1, S.bh0, acc10, 0,0,0);
        acc11 = __builtin_amdgcn_mfma_f32_16x16x32_bf16(S.al1, S.bh1, acc11, 0,0,0);
        acc00 = __builtin_amdgcn_mfma_f32_16x16x32_bf16(S.ah0, S.bl0, acc00, 0,0,0);
        acc01 = __builtin_amdgcn_mfma_f32_16x16x32_bf16(S.ah0, S.bl1, acc01, 0,0,0);
        acc10 = __builtin_amdgcn_mfma_f32_16x16x32_bf16(S.ah1, S.bl0, acc10, 0,0,0);
        acc11 = __builtin_amdgcn_mfma_f32_16x16x32_bf16(S.ah1, S.bl1, acc11, 0,0,0);
    };

    St SA, SB, SC;
    load_st(SA, 0); load_st(SB, 1); load_st(SC, 2);
    for (int s = 0; s < 33; s += 3) {
        do_mfma(SA); load_st(SA, s + 3);
        do_mfma(SB); load_st(SB, s + 4);
        do_mfma(SC); load_st(SC, s + 5);
    }
    do_mfma(SA); do_mfma(SB); do_mfma(SC);

    // ---- epilogue: C/D layout col=lane&15 (co), row=(lane>>4)*4+reg (x) ----
    const float* scp = ws + OFF_SCALE + b * 128;
    const float* bip = ws + OFF_BIAS  + b * 128;
    float* hout = ws + OFF_H;
    #pragma unroll
    for (int nf = 0; nf < 2; ++nf) {
        const int co = cobase + nf * 16 + lr;
        const float sc = 1.f + scp[co];
        const float bi = bip[co];
        const float cb = conv_b[co];
        #pragma unroll
        for (int mf = 0; mf < 2; ++mf) {
            f32x4 a = (nf == 0) ? (mf == 0 ? acc00 : acc10)
                                : (mf == 0 ? acc01 : acc11);
            float4 o;
            o.x = (a[0] + cb) * sc + bi;
            o.y = (a[1] + cb) * sc + bi;
            o.z = (a[2] + cb) * sc + bi;
            o.w = (a[3] + cb) * sc + bi;
            const int xo = x0 + mf * 16 + lg * 4;
            *(float4*)(hout + (size_t)(b * 128 + co) * NN + y * 64 + xo) = o;
        }
    }
}

// ---------------------------------------------------------------------------
// qkv (runs only if gamma != 0): q/k/v 1x1 convs from h.
// ---------------------------------------------------------------------------
__global__ __launch_bounds__(256)
void qkv_kernel(float* __restrict__ ws,
                const float* __restrict__ qw, const float* __restrict__ qb,
                const float* __restrict__ kw, const float* __restrict__ kb,
                const float* __restrict__ vw, const float* __restrict__ vb,
                const float* __restrict__ gamma) {
    if (gamma[0] == 0.f) return;
    const int b  = blockIdx.y;
    const int oc = blockIdx.x;   // 0..159: 16 q, 16 k, 128 v
    const float* wrow; float bias; float* dst;
    if (oc < 16)      { wrow = qw + (size_t)oc * 128;        bias = qb[oc];
                        dst = ws + OFF_Q + (size_t)(b * 16 + oc) * NN; }
    else if (oc < 32) { int c = oc - 16; wrow = kw + (size_t)c * 128; bias = kb[c];
                        dst = ws + OFF_K + (size_t)(b * 16 + c) * NN; }
    else              { int c = oc - 32; wrow = vw + (size_t)c * 128; bias = vb[c];
                        dst = ws + OFF_V + (size_t)(b * 128 + c) * NN; }
    const float* hb = ws + OFF_H + (size_t)b * 128 * NN;
    for (int n = threadIdx.x; n < NN; n += 256) {
        float a = bias;
        for (int ci = 0; ci < 128; ++ci) a += hb[(size_t)ci * NN + n] * wrow[ci];
        dst[n] = a;
    }
}

// ---------------------------------------------------------------------------
// attn (runs only if gamma != 0): flash-style, 64 queries per block.
// ---------------------------------------------------------------------------
__global__ __launch_bounds__(256)
void attn_kernel(float* __restrict__ ws, const float* __restrict__ gamma) {
    if (gamma[0] == 0.f) return;
    const int b  = blockIdx.y;
    const int n0 = blockIdx.x * 64;
    const int t  = threadIdx.x;

    __shared__ float q_s[16][64];
    __shared__ float k_s[16][64];
    __shared__ float v_s[64][129];
    __shared__ float p_s[64][65];
    __shared__ float m_run[64], l_run[64], sc_s[64];

    const float* qp = ws + OFF_Q + (size_t)b * 16 * NN;
    const float* kp = ws + OFF_K + (size_t)b * 16 * NN;
    const float* vp = ws + OFF_V + (size_t)b * 128 * NN;

    for (int idx = t; idx < 16 * 64; idx += 256) {
        int cq = idx >> 6, j = idx & 63;
        q_s[cq][j] = qp[(size_t)cq * NN + n0 + j];
    }
    if (t < 64) { m_run[t] = -1e30f; l_run[t] = 0.f; }

    const int n  = t & 63;
    const int cg = t >> 6;
    float acc[32];
    #pragma unroll
    for (int i = 0; i < 32; ++i) acc[i] = 0.f;
    __syncthreads();

    for (int mt = 0; mt < 64; ++mt) {
        const int m0 = mt * 64;
        for (int idx = t; idx < 16 * 64; idx += 256) {
            int cq = idx >> 6, j = idx & 63;
            k_s[cq][j] = kp[(size_t)cq * NN + m0 + j];
        }
        for (int idx = t; idx < 128 * 64; idx += 256) {
            int c = idx >> 6, j = idx & 63;
            v_s[j][c] = vp[(size_t)c * NN + m0 + j];
        }
        __syncthreads();
        {
            const int nn2   = t & 63;
            const int mbase = (t >> 6) * 16;
            for (int mi = 0; mi < 16; ++mi) {
                const int mm = mbase + mi;
                float s = 0.f;
                #pragma unroll
                for (int cq = 0; cq < 16; ++cq) s += q_s[cq][nn2] * k_s[cq][mm];
                p_s[nn2][mm] = s;
            }
        }
        __syncthreads();
        if (t < 64) {
            float mold = m_run[t];
            float mx = mold;
            for (int mm = 0; mm < 64; ++mm) mx = fmaxf(mx, p_s[t][mm]);
            float sc = expf(mold - mx);
            float rs = 0.f;
            for (int mm = 0; mm < 64; ++mm) {
                float p = expf(p_s[t][mm] - mx);
                p_s[t][mm] = p;
                rs += p;
            }
            l_run[t] = l_run[t] * sc + rs;
            m_run[t] = mx;
            sc_s[t]  = sc;
        }
        __syncthreads();
        {
            const float sc = sc_s[n];
            #pragma unroll
            for (int i = 0; i < 32; ++i) acc[i] *= sc;
            for (int mm = 0; mm < 64; ++mm) {
                const float p = p_s[n][mm];
                #pragma unroll
                for (int i = 0; i < 32; ++i) acc[i] += p * v_s[mm][cg * 32 + i];
            }
        }
        __syncthreads();
    }

    const float inv = 1.f / l_run[n];
    float* ao = ws + OFF_AO + (size_t)b * 128 * NN;
    for (int i = 0; i < 32; ++i)
        ao[(size_t)(cg * 32 + i) * NN + n0 + n] = acc[i] * inv;
}

// ---------------------------------------------------------------------------
// h2 = gamma*attn_out + h; InstanceNorm (biased var, eps=1e-5); LeakyReLU.
// ---------------------------------------------------------------------------
__global__ __launch_bounds__(256)
void inorm_lrelu(const float* __restrict__ ws,
                 const float* __restrict__ gamma,
                 float* __restrict__ out) {
    const int bc = blockIdx.x;      // b*128 + c
    const int t  = threadIdx.x;
    const float g = gamma[0];

    const float4* hp = (const float4*)(ws + OFF_H  + (size_t)bc * NN);
    const float4* ap = (const float4*)(ws + OFF_AO + (size_t)bc * NN);

    float4 v[4];
    #pragma unroll
    for (int i = 0; i < 4; ++i) {
        float4 hv = hp[t + 256 * i];
        if (g != 0.f) {
            float4 av = ap[t + 256 * i];
            hv.x += g * av.x; hv.y += g * av.y; hv.z += g * av.z; hv.w += g * av.w;
        }
        v[i] = hv;
    }

    float s1 = 0.f, s2 = 0.f;
    #pragma unroll
    for (int i = 0; i < 4; ++i) {
        s1 += v[i].x + v[i].y + v[i].z + v[i].w;
        s2 += v[i].x * v[i].x + v[i].y * v[i].y + v[i].z * v[i].z + v[i].w * v[i].w;
    }
    #pragma unroll
    for (int off = 32; off; off >>= 1) {
        s1 += __shfl_xor(s1, off);
        s2 += __shfl_xor(s2, off);
    }
    __shared__ float r1[4], r2[4];
    if ((t & 63) == 0) { r1[t >> 6] = s1; r2[t >> 6] = s2; }
    __syncthreads();
    const float S1 = r1[0] + r1[1] + r1[2] + r1[3];
    const float S2 = r2[0] + r2[1] + r2[2] + r2[3];
    const float mu  = S1 * (1.f / 4096.f);
    const float var = S2 * (1.f / 4096.f) - mu * mu;
    const float rs  = 1.f / sqrtf(var + EPSV);

    float4* op = (float4*)out + (size_t)bc * (NN / 4);
    #pragma unroll
    for (int i = 0; i < 4; ++i) {
        float4 o;
        o.x = (v[i].x - mu) * rs; o.x = o.x >= 0.f ? o.x : 0.2f * o.x;
        o.y = (v[i].y - mu) * rs; o.y = o.y >= 0.f ? o.y : 0.2f * o.y;
        o.z = (v[i].z - mu) * rs; o.z = o.z >= 0.f ? o.z : 0.2f * o.z;
        o.w = (v[i].w - mu) * rs; o.w = o.w >= 0.f ? o.w : 0.2f * o.w;
        op[t + 256 * i] = o;
    }
}

// ---------------------------------------------------------------------------
extern "C" void kernel_launch(void* const* d_in, const int* in_sizes, int n_in,
                              void* d_out, int out_size, void* d_ws, size_t ws_size,
                              hipStream_t stream) {
    const float* x      = (const float*)d_in[0];
    const float* style  = (const float*)d_in[1];
    const float* conv_w = (const float*)d_in[2];
    const float* conv_b = (const float*)d_in[3];
    const float* ss_w   = (const float*)d_in[4];
    const float* ss_b   = (const float*)d_in[5];
    const float* sb_w   = (const float*)d_in[6];
    const float* sb_b   = (const float*)d_in[7];
    const float* q_w    = (const float*)d_in[8];
    const float* q_b    = (const float*)d_in[9];
    const float* k_w    = (const float*)d_in[10];
    const float* k_b    = (const float*)d_in[11];
    const float* v_w    = (const float*)d_in[12];
    const float* v_b    = (const float*)d_in[13];
    const float* gamma  = (const float*)d_in[14];
    float* ws  = (float*)d_ws;
    float* out = (float*)d_out;

    prep<<<800, 256, 0, stream>>>(x, conv_w, style, ss_w, ss_b, sb_w, sb_b, ws);
    mfma_conv<<<dim3(64, 2, 4), 256, 0, stream>>>(ws, conv_b);
    qkv_kernel<<<dim3(160, 4), 256, 0, stream>>>(ws, q_w, q_b, k_w, k_b, v_w, v_b, gamma);
    attn_kernel<<<dim3(64, 4), 256, 0, stream>>>(ws, gamma);
    inorm_lrelu<<<512, 256, 0, stream>>>(ws, gamma, out);
}